// Round 5
// baseline (959.564 us; speedup 1.0000x reference)
//
#include <hip/hip_runtime.h>
#include <hip/hip_bf16.h>
#include <math.h>

#define S_TOT 1536
#define S0    1024
#define HID   1024
#define HEADS 16
#define HD    64
#define INTER 4096
#define NLAYERS 4
#define KCONV 768
#define EPSV  1e-5f
#define SCALEV 0.125f
#define QKS   2048   // fused rope'd q|k bf16 row stride

typedef __attribute__((ext_vector_type(8))) __bf16 bf16x8;
typedef __attribute__((ext_vector_type(8))) unsigned short u16x8;
typedef __attribute__((ext_vector_type(4))) float f32x4;
typedef __attribute__((address_space(1))) void gvoid;
typedef __attribute__((address_space(3))) void lvoid;

__device__ __forceinline__ ushort f2bf(float f) {
    union { float f; unsigned u; } v; v.f = f;
    unsigned u = v.u;
    return (ushort)((u + 0x7FFFu + ((u >> 16) & 1u)) >> 16);
}
__device__ __forceinline__ float bf2f(ushort b) {
    union { unsigned u; float f; } v; v.u = ((unsigned)b) << 16;
    return v.f;
}

// counted vmcnt wait with compile-time immediate
template<int N> __device__ __forceinline__ void wait_vm() {
    if constexpr (N == 0)      asm volatile("s_waitcnt vmcnt(0)" ::: "memory");
    else if constexpr (N == 2) asm volatile("s_waitcnt vmcnt(2)" ::: "memory");
    else if constexpr (N == 4) asm volatile("s_waitcnt vmcnt(4)" ::: "memory");
    else if constexpr (N == 8) asm volatile("s_waitcnt vmcnt(8)" ::: "memory");
    else                       asm volatile("s_waitcnt vmcnt(0)" ::: "memory");
}

// ---------------- weight converts ----------------
__global__ __launch_bounds__(256) void cvt_kernel(
    const float* __restrict__ src, ushort* __restrict__ dst, int n4)
{
    int i = blockIdx.x * 256 + threadIdx.x;
    if (i < n4) {
        float4 v = ((const float4*)src)[i];
        ushort4 o;
        o.x = f2bf(v.x); o.y = f2bf(v.y); o.z = f2bf(v.z); o.w = f2bf(v.w);
        ((ushort4*)dst)[i] = o;
    }
}

// fused per-layer weight convert: dst = [qkv(3M) | o(1M) | gu-interleaved(8M) | down(4M)]
// gate/up rows interleaved in 16-row blocks so (gate[c], up[c]) are same-lane in C-frag.
__global__ __launch_bounds__(256) void cvt_layer_kernel(
    const float* __restrict__ qw, const float* __restrict__ kw,
    const float* __restrict__ vw, const float* __restrict__ ow,
    const float* __restrict__ gw, const float* __restrict__ uw,
    const float* __restrict__ dw, ushort* __restrict__ dst)
{
    int i = blockIdx.x * 256 + threadIdx.x;   // 4-elem group, 4M groups
    int e = i << 2;
    const float* src; int off; size_t de;
    if      (e < (1  << 20)) { src = qw; off = e;             de = e; }
    else if (e < (2  << 20)) { src = kw; off = e - (1 << 20); de = e; }
    else if (e < (3  << 20)) { src = vw; off = e - (2 << 20); de = e; }
    else if (e < (4  << 20)) { src = ow; off = e - (3 << 20); de = e; }
    else if (e < (8  << 20)) {
        src = gw; off = e - (4 << 20);
        int chan = off >> 10, col = off & 1023;
        de = (size_t)(4 << 20) + (size_t)(((chan >> 4) << 5) + (chan & 15)) * 1024 + col;
    }
    else if (e < (12 << 20)) {
        src = uw; off = e - (8 << 20);
        int chan = off >> 10, col = off & 1023;
        de = (size_t)(4 << 20) + (size_t)(((chan >> 4) << 5) + 16 + (chan & 15)) * 1024 + col;
    }
    else                     { src = dw; off = e - (12 << 20); de = e; }
    float4 v = *(const float4*)(src + off);
    ushort4 o;
    o.x = f2bf(v.x); o.y = f2bf(v.y); o.z = f2bf(v.z); o.w = f2bf(v.w);
    *(ushort4*)(dst + de) = o;
}

// ---------------- im2col (bf16 out) ----------------
__global__ __launch_bounds__(256) void im2col_kernel(
    const float* __restrict__ img0, const float* __restrict__ img1,
    ushort* __restrict__ P)
{
    int s = blockIdx.x;
    const float* img; int W, ph, pw;
    if (s < S0) { img = img0; W = 512; ph = s >> 5; pw = s & 31; }
    else { int t = s - S0; img = img1; W = 256; ph = t >> 4; pw = t & 15; }
    for (int k = threadIdx.x; k < KCONV; k += 256) {
        int c = k >> 8; int r = k & 255; int y = r >> 4; int x = r & 15;
        P[(size_t)s * KCONV + k] =
            f2bf(img[(size_t)c * 512 * W + (size_t)(ph * 16 + y) * W + (pw * 16 + x)]);
    }
}

// ============ 2-phase double-buffered K-loop (shared macro-body) ============
#define GEMM2P_CORE(BM_, BN_, NLA_, NLB_)                                        \
    auto stage = [&](int b, int k0) {                                            \
        _Pragma("unroll")                                                        \
        for (int i_ = 0; i_ < NLA_; ++i_) {                                      \
            int idx = t + i_ * 256;                                              \
            int r_ = idx >> 2, c8_ = (idx & 3) << 3;                             \
            __builtin_amdgcn_global_load_lds(                                    \
                (gvoid*)(A + (size_t)(bm + r_) * K + k0 + c8_),                  \
                (lvoid*)(&As[b][idx * 8]), 16, 0, 0);                            \
        }                                                                        \
        _Pragma("unroll")                                                        \
        for (int i_ = 0; i_ < NLB_; ++i_) {                                      \
            int idx = t + i_ * 256;                                              \
            int r_ = idx >> 2, c8_ = (idx & 3) << 3;                             \
            __builtin_amdgcn_global_load_lds(                                    \
                (gvoid*)(B + (size_t)(bn + r_) * K + k0 + c8_),                  \
                (lvoid*)(&Bs[b][idx * 8]), 16, 0, 0);                            \
        }                                                                        \
    };

// ---------------- generic 2-phase GEMM: C[M][N] = A[M][K] * B[N][K]^T ----------------
template<int BM, int BN, bool OUT_BF16>
__global__ __launch_bounds__(256) void gemm2p(
    const ushort* __restrict__ A, const ushort* __restrict__ B,
    void* __restrict__ Cout, int M, int N, int K)
{
    constexpr int WMT = BM / 32, WNT = BN / 32;
    constexpr int NLA = (BM * 32) / (8 * 256);
    constexpr int NLB = (BN * 32) / (8 * 256);
    constexpr int NL  = NLA + NLB;
    __shared__ ushort As[2][BM * 32];
    __shared__ ushort Bs[2][BN * 32];
    const int t = threadIdx.x;
    const int bm = blockIdx.x * BM, bn = blockIdx.y * BN;
    const int wave = t >> 6, lane = t & 63;
    const int wm = (wave & 1) * (BM / 2), wn = (wave >> 1) * (BN / 2);
    const int frow = lane & 15, fq = lane >> 4;
    GEMM2P_CORE(BM, BN, NLA, NLB)

    f32x4 acc[WMT][WNT];
    #pragma unroll
    for (int i = 0; i < WMT; ++i)
        #pragma unroll
        for (int j = 0; j < WNT; ++j) acc[i][j] = (f32x4){0.f, 0.f, 0.f, 0.f};

    stage(0, 0);
    int cur = 0;
    for (int k0 = 0; k0 < K; k0 += 32) {
        const bool more = (k0 + 32) < K;
        if (more) { stage(cur ^ 1, k0 + 32); wait_vm<NL>(); }
        else      { wait_vm<0>(); }
        __builtin_amdgcn_s_barrier();
        __builtin_amdgcn_sched_barrier(0);
        bf16x8 af[WMT], bfr[WNT];
        #pragma unroll
        for (int i = 0; i < WMT; ++i)
            af[i] = *(const bf16x8*)(&As[cur][(wm + 16 * i + frow) * 32 + fq * 8]);
        #pragma unroll
        for (int j = 0; j < WNT; ++j)
            bfr[j] = *(const bf16x8*)(&Bs[cur][(wn + 16 * j + frow) * 32 + fq * 8]);
        asm volatile("s_waitcnt lgkmcnt(0)" ::: "memory");
        __builtin_amdgcn_sched_barrier(0);
        __builtin_amdgcn_s_barrier();
        #pragma unroll
        for (int i = 0; i < WMT; ++i)
            #pragma unroll
            for (int j = 0; j < WNT; ++j)
                acc[i][j] = __builtin_amdgcn_mfma_f32_16x16x32_bf16(
                    af[i], bfr[j], acc[i][j], 0, 0, 0);
        cur ^= 1;
    }
    #pragma unroll
    for (int i = 0; i < WMT; ++i) {
        #pragma unroll
        for (int j = 0; j < WNT; ++j) {
            #pragma unroll
            for (int r = 0; r < 4; ++r) {
                int row = bm + wm + 16 * i + fq * 4 + r;
                int col = bn + wn + 16 * j + frow;
                float vv = acc[i][j][r];
                if (OUT_BF16) ((ushort*)Cout)[(size_t)row * N + col] = f2bf(vv);
                else          ((float*)Cout)[(size_t)row * N + col] = vv;
            }
        }
    }
}

// ---------------- qkv GEMM (128x128) with fused RoPE epilogue ----------------
__global__ __launch_bounds__(256) void gemm2p_qkv(
    const ushort* __restrict__ A, const ushort* __restrict__ B,
    ushort* __restrict__ qkb, ushort* __restrict__ vb,
    const float* __restrict__ cs, const float* __restrict__ sn, int K)
{
    constexpr int BM = 128, BN = 128;
    __shared__ ushort As[2][BM * 32];
    __shared__ ushort Bs[2][BN * 32];
    const int t = threadIdx.x;
    const int bm = blockIdx.x * BM, bn = blockIdx.y * BN;
    const int wave = t >> 6, lane = t & 63;
    const int wm = (wave & 1) * 64, wn = (wave >> 1) * 64;
    const int frow = lane & 15, fq = lane >> 4;
    GEMM2P_CORE(BM, BN, 2, 2)

    f32x4 acc[4][4];
    #pragma unroll
    for (int i = 0; i < 4; ++i)
        #pragma unroll
        for (int j = 0; j < 4; ++j) acc[i][j] = (f32x4){0.f, 0.f, 0.f, 0.f};

    stage(0, 0);
    int cur = 0;
    for (int k0 = 0; k0 < K; k0 += 32) {
        const bool more = (k0 + 32) < K;
        if (more) { stage(cur ^ 1, k0 + 32); wait_vm<4>(); }
        else      { wait_vm<0>(); }
        __builtin_amdgcn_s_barrier();
        __builtin_amdgcn_sched_barrier(0);
        bf16x8 af[4], bfr[4];
        #pragma unroll
        for (int i = 0; i < 4; ++i)
            af[i] = *(const bf16x8*)(&As[cur][(wm + 16 * i + frow) * 32 + fq * 8]);
        #pragma unroll
        for (int j = 0; j < 4; ++j)
            bfr[j] = *(const bf16x8*)(&Bs[cur][(wn + 16 * j + frow) * 32 + fq * 8]);
        asm volatile("s_waitcnt lgkmcnt(0)" ::: "memory");
        __builtin_amdgcn_sched_barrier(0);
        __builtin_amdgcn_s_barrier();
        #pragma unroll
        for (int i = 0; i < 4; ++i)
            #pragma unroll
            for (int j = 0; j < 4; ++j)
                acc[i][j] = __builtin_amdgcn_mfma_f32_16x16x32_bf16(
                    af[i], bfr[j], acc[i][j], 0, 0, 0);
        cur ^= 1;
    }
    const int colbase = bn + wn;
    const int part = colbase >> 10;       // 0=q, 1=k, 2=v
    if (part < 2) {
        #pragma unroll
        for (int i = 0; i < 4; ++i) {
            #pragma unroll
            for (int r = 0; r < 4; ++r) {
                int row = bm + wm + 16 * i + fq * 4 + r;
                float cv0 = cs[row * 32 + frow],      sv0 = sn[row * 32 + frow];
                float cv1 = cs[row * 32 + 16 + frow], sv1 = sn[row * 32 + 16 + frow];
                float xa0 = acc[i][0][r], xa1 = acc[i][1][r];
                float xb0 = acc[i][2][r], xb1 = acc[i][3][r];
                ushort* dst = qkb + (size_t)row * QKS + (part << 10) + (colbase & 1023) + frow;
                dst[0]  = f2bf(xa0 * cv0 - xb0 * sv0);
                dst[16] = f2bf(xa1 * cv1 - xb1 * sv1);
                dst[32] = f2bf(xb0 * cv0 + xa0 * sv0);
                dst[48] = f2bf(xb1 * cv1 + xa1 * sv1);
            }
        }
    } else {
        #pragma unroll
        for (int i = 0; i < 4; ++i)
            #pragma unroll
            for (int j = 0; j < 4; ++j)
                #pragma unroll
                for (int r = 0; r < 4; ++r) {
                    int row = bm + wm + 16 * i + fq * 4 + r;
                    vb[(size_t)row * 1024 + (colbase & 1023) + 16 * j + frow] =
                        f2bf(acc[i][j][r]);
                }
    }
}

// ======== gate/up GEMM: 256x256 tile, BK=32, 3-buffer depth-2 pipeline ========
// 8 waves (512 thr), per-wave 128x64 output, 96 KiB LDS. One barrier + counted
// vmcnt per K-step: steady state vmcnt(4) (2 tiles in flight, oldest landed),
// final iteration vmcnt(0) -- exact tail drain. Stage of kt+2 issued AFTER the
// barrier into buffer (kt+2)%3, last read at kt-1 (ds_reads retire in-order
// before the consuming MFMAs, which precede the barrier -> provably free).
// LDS swizzle: logical col8 lc at phys slot lc^(r&3); inverse-swizzled GLOBAL
// source + swizzled ds_read (both-sides rule), linear gload_lds dest.
__global__ __launch_bounds__(512, 2) void gemm_gu8(
    const ushort* __restrict__ A, const ushort* __restrict__ B,
    ushort* __restrict__ gb, int K)
{
    __shared__ ushort As[3][256 * 32];
    __shared__ ushort Bs[3][256 * 32];
    const int t = threadIdx.x;
    // bijective XCD chunking: 192 blocks, 24 consecutive per XCD
    int wg = blockIdx.x + gridDim.x * blockIdx.y;
    int q = (gridDim.x * gridDim.y) >> 3;
    int wgs = (wg & 7) * q + (wg >> 3);
    const int bm = (wgs % gridDim.x) * 256;
    const int bn = (wgs / gridDim.x) * 256;
    const int wave = t >> 6, lane = t & 63;
    const int wm = (wave >> 2) * 128, wn = (wave & 3) * 64;
    const int frow = lane & 15, fq = lane >> 4;

    auto stage = [&](int b, int k0) {
        #pragma unroll
        for (int i = 0; i < 2; ++i) {
            int sl = t + (i << 9);            // 16B-slot id, 0..1023
            int r = sl >> 2, sp = sl & 3;
            int lc = sp ^ (r & 3);            // inverse-swizzled logical col8
            __builtin_amdgcn_global_load_lds(
                (gvoid*)(A + (size_t)(bm + r) * K + k0 + (lc << 3)),
                (lvoid*)(&As[b][sl * 8]), 16, 0, 0);
            __builtin_amdgcn_global_load_lds(
                (gvoid*)(B + (size_t)(bn + r) * K + k0 + (lc << 3)),
                (lvoid*)(&Bs[b][sl * 8]), 16, 0, 0);
        }
    };

    f32x4 acc[8][4];
    #pragma unroll
    for (int i = 0; i < 8; ++i)
        #pragma unroll
        for (int j = 0; j < 4; ++j) acc[i][j] = (f32x4){0.f, 0.f, 0.f, 0.f};

    const int NKT = K >> 5;                   // 32 for K=1024
    stage(0, 0); stage(1, 32);
    int cbuf = 0, sbuf = 2;
    for (int kt = 0; kt < NKT; ++kt) {
        if (kt + 1 < NKT) wait_vm<4>();       // tile kt landed; kt+1 may be in flight
        else              wait_vm<0>();       // last tile: full drain
        __builtin_amdgcn_sched_barrier(0);
        __builtin_amdgcn_s_barrier();
        __builtin_amdgcn_sched_barrier(0);
        if (kt + 2 < NKT) {
            stage(sbuf, (kt + 2) << 5);
            sbuf = (sbuf == 2) ? 0 : sbuf + 1;
        }
        bf16x8 af[8], bfr[4];
        #pragma unroll
        for (int i = 0; i < 8; ++i) {
            int ar = wm + (i << 4) + frow;
            af[i] = *(const bf16x8*)(&As[cbuf][(ar << 5) + ((fq ^ (ar & 3)) << 3)]);
        }
        #pragma unroll
        for (int j = 0; j < 4; ++j) {
            int br = wn + (j << 4) + frow;
            bfr[j] = *(const bf16x8*)(&Bs[cbuf][(br << 5) + ((fq ^ (br & 3)) << 3)]);
        }
        __builtin_amdgcn_s_setprio(1);
        #pragma unroll
        for (int i = 0; i < 8; ++i)
            #pragma unroll
            for (int j = 0; j < 4; ++j)
                acc[i][j] = __builtin_amdgcn_mfma_f32_16x16x32_bf16(
                    af[i], bfr[j], acc[i][j], 0, 0, 0);
        __builtin_amdgcn_s_setprio(0);
        cbuf = (cbuf == 2) ? 0 : cbuf + 1;
    }
    // fused SiLU epilogue: abs 16-col block even = gate, odd = up (same lane)
    #pragma unroll
    for (int i = 0; i < 8; ++i) {
        #pragma unroll
        for (int p = 0; p < 2; ++p) {
            int chan = ((bn + wn) >> 1) + p * 16 + frow;
            #pragma unroll
            for (int r = 0; r < 4; ++r) {
                int row = bm + wm + (i << 4) + (fq << 2) + r;
                float g = acc[i][2 * p][r], u = acc[i][2 * p + 1][r];
                float sg = 1.f / (1.f + __expf(-g));
                gb[(size_t)row * INTER + chan] = f2bf(g * sg * u);
            }
        }
    }
}

// ============ 2-phase split-K GEMM: writes f32 partial slabs (no atomics) ============
template<int SPLITK>
__global__ __launch_bounds__(256) void gemm2p_sk(
    const ushort* __restrict__ A, const ushort* __restrict__ B,
    float* __restrict__ P, int M, int N, int K)
{
    constexpr int BM = 128, BN = 128;
    __shared__ ushort As[2][BM * 32];
    __shared__ ushort Bs[2][BN * 32];
    const int t = threadIdx.x;
    const int bm = blockIdx.x * BM, bn = blockIdx.y * BN;
    const int kc = K / SPLITK;
    const int kb = blockIdx.z * kc, ke = kb + kc;
    const int wave = t >> 6, lane = t & 63;
    const int wm = (wave & 1) * 64, wn = (wave >> 1) * 64;
    const int frow = lane & 15, fq = lane >> 4;
    GEMM2P_CORE(BM, BN, 2, 2)

    f32x4 acc[4][4];
    #pragma unroll
    for (int i = 0; i < 4; ++i)
        #pragma unroll
        for (int j = 0; j < 4; ++j) acc[i][j] = (f32x4){0.f, 0.f, 0.f, 0.f};

    stage(0, kb);
    int cur = 0;
    for (int k0 = kb; k0 < ke; k0 += 32) {
        const bool more = (k0 + 32) < ke;
        if (more) { stage(cur ^ 1, k0 + 32); wait_vm<4>(); }
        else      { wait_vm<0>(); }
        __builtin_amdgcn_s_barrier();
        __builtin_amdgcn_sched_barrier(0);
        bf16x8 af[4], bfr[4];
        #pragma unroll
        for (int i = 0; i < 4; ++i)
            af[i] = *(const bf16x8*)(&As[cur][(wm + 16 * i + frow) * 32 + fq * 8]);
        #pragma unroll
        for (int j = 0; j < 4; ++j)
            bfr[j] = *(const bf16x8*)(&Bs[cur][(wn + 16 * j + frow) * 32 + fq * 8]);
        asm volatile("s_waitcnt lgkmcnt(0)" ::: "memory");
        __builtin_amdgcn_sched_barrier(0);
        __builtin_amdgcn_s_barrier();
        #pragma unroll
        for (int i = 0; i < 4; ++i)
            #pragma unroll
            for (int j = 0; j < 4; ++j)
                acc[i][j] = __builtin_amdgcn_mfma_f32_16x16x32_bf16(
                    af[i], bfr[j], acc[i][j], 0, 0, 0);
        cur ^= 1;
    }
    float* Pz = P + (size_t)blockIdx.z * M * N;
    #pragma unroll
    for (int i = 0; i < 4; ++i) {
        #pragma unroll
        for (int j = 0; j < 4; ++j) {
            #pragma unroll
            for (int r = 0; r < 4; ++r) {
                int row = bm + wm + 16 * i + fq * 4 + r;
                int col = bn + wn + 16 * j + frow;
                Pz[(size_t)row * N + col] = acc[i][j][r];
            }
        }
    }
}

// x[i] += P0[i] + P1[i] + P2[i] + P3[i]  (float4 vectorized; n4 = n/4)
__global__ __launch_bounds__(256) void reduce4_kernel(
    const float* __restrict__ P, float* __restrict__ x, int n4)
{
    int i = blockIdx.x * 256 + threadIdx.x;
    if (i >= n4) return;
    const int n = n4 << 2;
    float4 a  = ((const float4*)x)[i];
    float4 p0 = ((const float4*)P)[i];
    float4 p1 = ((const float4*)(P + (size_t)n))[i];
    float4 p2 = ((const float4*)(P + (size_t)2 * n))[i];
    float4 p3 = ((const float4*)(P + (size_t)3 * n))[i];
    a.x += p0.x + p1.x + p2.x + p3.x;
    a.y += p0.y + p1.y + p2.y + p3.y;
    a.z += p0.z + p1.z + p2.z + p3.z;
    a.w += p0.w + p1.w + p2.w + p3.w;
    ((float4*)x)[i] = a;
}

// fused: x += sum(4 partials); hnb = rms(x)*w   (one block per row)
__global__ __launch_bounds__(256) void reduce_rms_bf_kernel(
    const float* __restrict__ P, float* __restrict__ x,
    const float* __restrict__ w, ushort* __restrict__ out)
{
    int row = blockIdx.x, t = threadIdx.x;
    size_t off = (size_t)row * HID + t * 4;
    float4 a = *(const float4*)(x + off);
    #pragma unroll
    for (int z = 0; z < 4; ++z) {
        float4 p = *(const float4*)(P + (size_t)z * S_TOT * HID + off);
        a.x += p.x; a.y += p.y; a.z += p.z; a.w += p.w;
    }
    *(float4*)(x + off) = a;
    float ss = a.x * a.x + a.y * a.y + a.z * a.z + a.w * a.w;
    #pragma unroll
    for (int o = 32; o > 0; o >>= 1) ss += __shfl_down(ss, o, 64);
    __shared__ float red[4];
    int wid = t >> 6;
    if ((t & 63) == 0) red[wid] = ss;
    __syncthreads();
    if (t == 0)
        red[0] = rsqrtf((red[0] + red[1] + red[2] + red[3]) / HID + EPSV);
    __syncthreads();
    float rs = red[0];
    const float* wp = w + t * 4;
    ushort4 o4;
    o4.x = f2bf(a.x * rs * wp[0]); o4.y = f2bf(a.y * rs * wp[1]);
    o4.z = f2bf(a.z * rs * wp[2]); o4.w = f2bf(a.w * rs * wp[3]);
    *(ushort4*)(out + off) = o4;
}

// ---------------- RMS norm fp32->fp32 ----------------
__global__ __launch_bounds__(256) void rms_kernel(
    const float* __restrict__ in, const float* __restrict__ w,
    float* __restrict__ out)
{
    int row = blockIdx.x;
    const float* xr = in + (size_t)row * HID;
    float ss = 0.f;
    for (int i = threadIdx.x; i < HID; i += 256) { float v = xr[i]; ss += v * v; }
    #pragma unroll
    for (int off = 32; off > 0; off >>= 1) ss += __shfl_down(ss, off, 64);
    __shared__ float red[4];
    int wid = threadIdx.x >> 6;
    if ((threadIdx.x & 63) == 0) red[wid] = ss;
    __syncthreads();
    if (threadIdx.x == 0)
        red[0] = rsqrtf((red[0] + red[1] + red[2] + red[3]) / HID + EPSV);
    __syncthreads();
    float rs = red[0];
    for (int i = threadIdx.x; i < HID; i += 256)
        out[(size_t)row * HID + i] = xr[i] * rs * w[i];
}

// ---------------- RMS norm fp32->bf16 ----------------
__global__ __launch_bounds__(256) void rms_bf_kernel(
    const float* __restrict__ in, const float* __restrict__ w,
    ushort* __restrict__ out)
{
    int row = blockIdx.x;
    const float* xr = in + (size_t)row * HID;
    float ss = 0.f;
    for (int i = threadIdx.x; i < HID; i += 256) { float v = xr[i]; ss += v * v; }
    #pragma unroll
    for (int off = 32; off > 0; off >>= 1) ss += __shfl_down(ss, off, 64);
    __shared__ float red[4];
    int wid = threadIdx.x >> 6;
    if ((threadIdx.x & 63) == 0) red[wid] = ss;
    __syncthreads();
    if (threadIdx.x == 0)
        red[0] = rsqrtf((red[0] + red[1] + red[2] + red[3]) / HID + EPSV);
    __syncthreads();
    float rs = red[0];
    for (int i = threadIdx.x; i < HID; i += 256)
        out[(size_t)row * HID + i] = f2bf(xr[i] * rs * w[i]);
}

// ---------------- RoPE tables ----------------
__global__ void rope_tab_kernel(float* __restrict__ cs, float* __restrict__ sn)
{
    int s = blockIdx.x; int j = threadIdx.x; // 32 threads
    int h, w;
    if (s < S0) { h = s >> 5; w = s & 31; }
    else { int t = s - S0; h = t >> 4; w = t & 15; }
    float f;
    if (j < 16) f = (float)h * powf(10000.f, -(4.f * j) / 64.f);
    else        f = (float)w * powf(10000.f, -(4.f * (j - 16) + 2.f) / 64.f);
    cs[s * 32 + j] = cosf(f);
    sn[s * 32 + j] = sinf(f);
}

// ---------------- V transpose bf16 vb[s][1024] -> bf16 vT[head][d][s] ----------------
__global__ __launch_bounds__(256) void vtrans_bf_kernel(
    const ushort* __restrict__ vb, ushort* __restrict__ vT)
{
    __shared__ ushort T[64][72];
    int st = blockIdx.x;   // s-tile (24)
    int hh = blockIdx.y;   // head
    int s0 = st << 6;
    int t = threadIdx.x;
    #pragma unroll
    for (int i = 0; i < 2; ++i) {
        int u = t + (i << 8);
        int r = u >> 3, c8 = (u & 7) << 3;
        u16x8 v = *(const u16x8*)(vb + (size_t)(s0 + r) * 1024 + hh * HD + c8);
        *(u16x8*)(&T[r][c8]) = v;
    }
    __syncthreads();
    int d = t >> 2, sg = (t & 3) << 4;
    ushort buf[16];
    #pragma unroll
    for (int j = 0; j < 16; ++j) buf[j] = T[sg + j][d];
    ushort* dst = vT + ((size_t)hh * HD + d) * S_TOT + s0 + sg;
    *(u16x8*)dst = *(u16x8*)buf;
    *(u16x8*)(dst + 8) = *(u16x8*)(buf + 8);
}

// ---------------- MFMA flash attention ----------------
__global__ __launch_bounds__(256) void flash_mfma_kernel(
    const ushort* __restrict__ qkb, const ushort* __restrict__ vT,
    ushort* __restrict__ o)
{
    __shared__ ushort Ks[64 * 72];
    __shared__ ushort Vt[64 * 72];
    __shared__ ushort Ps[4 * 16 * 72];
    int tile = blockIdx.x;
    int hh = blockIdx.y;
    int segStart, q0, nkt;
    if (tile < 16) { segStart = 0; q0 = tile << 6; nkt = 16; }
    else { segStart = S0; q0 = S0 + ((tile - 16) << 6); nkt = 8; }
    const int t = threadIdx.x;
    const int wave = t >> 6, lane = t & 63;
    const int c = lane & 15, fq = lane >> 4;
    const int wq = wave << 4;
    ushort* Pw = Ps + wave * 16 * 72;

    bf16x8 qf[2];
    #pragma unroll
    for (int ks = 0; ks < 2; ++ks)
        qf[ks] = *(const bf16x8*)(qkb + (size_t)(q0 + wq + c) * QKS + hh * HD + ks * 32 + fq * 8);

    float m_i[4], l_i[4];
    f32x4 accO[4];
    #pragma unroll
    for (int r = 0; r < 4; ++r) { m_i[r] = -1e30f; l_i[r] = 0.f; }
    #pragma unroll
    for (int nt = 0; nt < 4; ++nt) accO[nt] = (f32x4){0.f, 0.f, 0.f, 0.f};

    for (int kt = 0; kt < nkt; ++kt) {
        int kbase = segStart + (kt << 6);
        __syncthreads();
        #pragma unroll
        for (int i = 0; i < 2; ++i) {
            int u = t + (i << 8);
            int r = u >> 3, c8 = (u & 7) << 3;
            u16x8 kv = *(const u16x8*)(qkb + (size_t)(kbase + r) * QKS + 1024 + hh * HD + c8);
            *(u16x8*)(Ks + r * 72 + c8) = kv;
            u16x8 vv = *(const u16x8*)(vT + ((size_t)hh * HD + r) * S_TOT + kbase + c8);
            *(u16x8*)(Vt + r * 72 + c8) = vv;
        }
        __syncthreads();

        f32x4 acc[4];
        #pragma unroll
        for (int nt = 0; nt < 4; ++nt) acc[nt] = (f32x4){0.f, 0.f, 0.f, 0.f};
        #pragma unroll
        for (int ks = 0; ks < 2; ++ks) {
            #pragma unroll
            for (int nt = 0; nt < 4; ++nt) {
                bf16x8 bfr = *(const bf16x8*)(Ks + (nt * 16 + c) * 72 + ks * 32 + fq * 8);
                acc[nt] = __builtin_amdgcn_mfma_f32_16x16x32_bf16(qf[ks], bfr, acc[nt], 0, 0, 0);
            }
        }

        #pragma unroll
        for (int r = 0; r < 4; ++r) {
            float s0v = acc[0][r] * SCALEV, s1v = acc[1][r] * SCALEV;
            float s2v = acc[2][r] * SCALEV, s3v = acc[3][r] * SCALEV;
            float rm = fmaxf(fmaxf(s0v, s1v), fmaxf(s2v, s3v));
            #pragma unroll
            for (int msk = 1; msk < 16; msk <<= 1)
                rm = fmaxf(rm, __shfl_xor(rm, msk, 64));
            float mn = fmaxf(m_i[r], rm);
            float al = __expf(m_i[r] - mn);
            float p0 = __expf(s0v - mn), p1 = __expf(s1v - mn);
            float p2 = __expf(s2v - mn), p3 = __expf(s3v - mn);
            float rs = p0 + p1 + p2 + p3;
            #pragma unroll
            for (int msk = 1; msk < 16; msk <<= 1)
                rs += __shfl_xor(rs, msk, 64);
            l_i[r] = l_i[r] * al + rs;
            m_i[r] = mn;
            #pragma unroll
            for (int nt = 0; nt < 4; ++nt) accO[nt][r] *= al;
            int qrow = (fq << 2) + r;
            Pw[qrow * 72 + 0  + c] = f2bf(p0);
            Pw[qrow * 72 + 16 + c] = f2bf(p1);
            Pw[qrow * 72 + 32 + c] = f2bf(p2);
            Pw[qrow * 72 + 48 + c] = f2bf(p3);
        }

        #pragma unroll
        for (int ks = 0; ks < 2; ++ks) {
            bf16x8 pa = *(const bf16x8*)(Pw + c * 72 + ks * 32 + fq * 8);
            #pragma unroll
            for (int nt = 0; nt < 4; ++nt) {
                bf16x8 bv = *(const bf16x8*)(Vt + (nt * 16 + c) * 72 + ks * 32 + fq * 8);
                accO[nt] = __builtin_amdgcn_mfma_f32_16x16x32_bf16(pa, bv, accO[nt], 0, 0, 0);
            }
        }
    }

    #pragma unroll
    for (int r = 0; r < 4; ++r) {
        float inv = 1.f / l_i[r];
        int row = q0 + wq + (fq << 2) + r;
        #pragma unroll
        for (int nt = 0; nt < 4; ++nt)
            o[(size_t)row * HID + hh * HD + nt * 16 + c] = f2bf(accO[nt][r] * inv);
    }
}

// ---------------- copy to out ----------------
__global__ __launch_bounds__(256) void copy_kernel(
    const float* __restrict__ src, float* __restrict__ dst, int n)
{
    int i = blockIdx.x * 256 + threadIdx.x;
    if (i < n) dst[i] = src[i];
}

extern "C" void kernel_launch(void* const* d_in, const int* in_sizes, int n_in,
                              void* d_out, int out_size, void* d_ws, size_t ws_size,
                              hipStream_t stream)
{
    const float* img0        = (const float*)d_in[0];
    const float* img1        = (const float*)d_in[1];
    const float* conv_w      = (const float*)d_in[2];
    const float* ln_pre_w    = (const float*)d_in[3];
    const float* attn_norm_w = (const float*)d_in[4];
    const float* q_w         = (const float*)d_in[5];
    const float* k_w         = (const float*)d_in[6];
    const float* v_w         = (const float*)d_in[7];
    const float* o_w         = (const float*)d_in[8];
    const float* ffn_norm_w  = (const float*)d_in[9];
    const float* gate_w      = (const float*)d_in[10];
    const float* up_w        = (const float*)d_in[11];
    const float* down_w      = (const float*)d_in[12];

    char* p = (char*)d_ws;
    float* x    = (float*)p;   p += (size_t)1572864 * 4;   // [1536][1024]
    float* cs   = (float*)p;   p += (size_t)49152 * 4;
    float* sn   = (float*)p;   p += (size_t)49152 * 4;
    ushort* qkb = (ushort*)p;  p += (size_t)3145728 * 2;   // [1536][2048] rope'd q|k bf16
    ushort* vb  = (ushort*)p;  p += (size_t)1572864 * 2;   // [1536][1024] v bf16
    ushort* vTb = (ushort*)p;  p += (size_t)1572864 * 2;   // [16][64][1536] V^T bf16
    ushort* hnb = (ushort*)p;  p += (size_t)1572864 * 2;   // [1536][1024]
    ushort* obb = (ushort*)p;  p += (size_t)1572864 * 2;   // [1536][1024]
    ushort* gb  = (ushort*)p;  p += (size_t)6291456 * 2;   // [1536][4096] silu(g)*u bf16
    float* skP  = (float*)p;   p += (size_t)6291456 * 4;   // 4 x [1536][1024] f32 partials
    ushort* Pb  = (ushort*)p;  p += (size_t)1179648 * 2;   // [1536][768]
    ushort* cvb = (ushort*)p;  p += (size_t)786432 * 2;    // conv_w bf16
    ushort* wbuf= (ushort*)p;  p += (size_t)16777216 * 2;  // per-layer weights

    ushort* wqkv = wbuf;                 // [3072][1024]
    ushort* wo   = wbuf + 3145728;       // [1024][1024]
    ushort* wgu  = wbuf + 4194304;       // [8192][1024] gu-interleaved
    ushort* wdn  = wbuf + 12582912;      // [1024][4096]

    dim3 blk(256);

    cvt_kernel<<<768, blk, 0, stream>>>(conv_w, cvb, 786432 / 4);
    im2col_kernel<<<S_TOT, blk, 0, stream>>>(img0, img1, Pb);
    gemm2p<64, 64, false><<<dim3(24, 16), blk, 0, stream>>>(
        Pb, cvb, x, S_TOT, HID, KCONV);
    rms_kernel<<<S_TOT, blk, 0, stream>>>(x, ln_pre_w, x);
    rope_tab_kernel<<<S_TOT, 32, 0, stream>>>(cs, sn);

    for (int l = 0; l < NLAYERS; ++l) {
        cvt_layer_kernel<<<16384, blk, 0, stream>>>(
            q_w + (size_t)l * 1048576, k_w + (size_t)l * 1048576,
            v_w + (size_t)l * 1048576, o_w + (size_t)l * 1048576,
            gate_w + (size_t)l * 4194304, up_w + (size_t)l * 4194304,
            down_w + (size_t)l * 4194304, wbuf);

        rms_bf_kernel<<<S_TOT, blk, 0, stream>>>(x, attn_norm_w + (size_t)l * HID, hnb);
        gemm2p_qkv<<<dim3(12, 24), blk, 0, stream>>>(
            hnb, wqkv, qkb, vb, cs, sn, HID);
        vtrans_bf_kernel<<<dim3(24, HEADS), blk, 0, stream>>>(vb, vTb);
        flash_mfma_kernel<<<dim3(24, HEADS), blk, 0, stream>>>(qkb, vTb, obb);
        // o-projection: split-K partials, then fused (x += sum) + rms -> hnb
        gemm2p_sk<4><<<dim3(12, 8, 4), blk, 0, stream>>>(
            obb, wo, skP, S_TOT, HID, HID);
        reduce_rms_bf_kernel<<<S_TOT, blk, 0, stream>>>(
            skP, x, ffn_norm_w + (size_t)l * HID, hnb);
        // gate/up GEMM: 256^2 deep-pipelined (3-buf), fused SiLU -> gb bf16
        gemm_gu8<<<dim3(6, 32), dim3(512), 0, stream>>>(hnb, wgu, gb, HID);
        // down-projection: split-K=4 partials + reduce
        gemm2p_sk<4><<<dim3(12, 8, 4), blk, 0, stream>>>(
            gb, wdn, skP, S_TOT, HID, INTER);
        reduce4_kernel<<<1536, blk, 0, stream>>>(skP, x, S_TOT * HID / 4);
    }
    copy_kernel<<<(S_TOT * HID) / 256, blk, 0, stream>>>(x, (float*)d_out, S_TOT * HID);
}

// Round 6
// 918.799 us; speedup vs baseline: 1.0444x; 1.0444x over previous
//
#include <hip/hip_runtime.h>
#include <hip/hip_bf16.h>
#include <math.h>

#define S_TOT 1536
#define S0    1024
#define HID   1024
#define HEADS 16
#define HD    64
#define INTER 4096
#define NLAYERS 4
#define KCONV 768
#define EPSV  1e-5f
#define SCALEV 0.125f
#define QKS   2048   // fused rope'd q|k bf16 row stride

typedef __attribute__((ext_vector_type(8))) __bf16 bf16x8;
typedef __attribute__((ext_vector_type(8))) unsigned short u16x8;
typedef __attribute__((ext_vector_type(4))) float f32x4;
typedef __attribute__((address_space(1))) void gvoid;
typedef __attribute__((address_space(3))) void lvoid;

__device__ __forceinline__ ushort f2bf(float f) {
    union { float f; unsigned u; } v; v.f = f;
    unsigned u = v.u;
    return (ushort)((u + 0x7FFFu + ((u >> 16) & 1u)) >> 16);
}
__device__ __forceinline__ float bf2f(ushort b) {
    union { unsigned u; float f; } v; v.u = ((unsigned)b) << 16;
    return v.f;
}

// counted vmcnt wait with compile-time immediate
template<int N> __device__ __forceinline__ void wait_vm() {
    if constexpr (N == 0)      asm volatile("s_waitcnt vmcnt(0)" ::: "memory");
    else if constexpr (N == 2) asm volatile("s_waitcnt vmcnt(2)" ::: "memory");
    else if constexpr (N == 4) asm volatile("s_waitcnt vmcnt(4)" ::: "memory");
    else if constexpr (N == 8) asm volatile("s_waitcnt vmcnt(8)" ::: "memory");
    else                       asm volatile("s_waitcnt vmcnt(0)" ::: "memory");
}

// ---------------- weight converts ----------------
__global__ __launch_bounds__(256) void cvt_kernel(
    const float* __restrict__ src, ushort* __restrict__ dst, int n4)
{
    int i = blockIdx.x * 256 + threadIdx.x;
    if (i < n4) {
        float4 v = ((const float4*)src)[i];
        ushort4 o;
        o.x = f2bf(v.x); o.y = f2bf(v.y); o.z = f2bf(v.z); o.w = f2bf(v.w);
        ((ushort4*)dst)[i] = o;
    }
}

// fused per-layer weight convert: dst = [qkv(3M) | o(1M) | gu-interleaved(8M) | down(4M)]
// gate/up rows interleaved in 16-row blocks so (gate[c], up[c]) are same-lane in C-frag.
__global__ __launch_bounds__(256) void cvt_layer_kernel(
    const float* __restrict__ qw, const float* __restrict__ kw,
    const float* __restrict__ vw, const float* __restrict__ ow,
    const float* __restrict__ gw, const float* __restrict__ uw,
    const float* __restrict__ dw, ushort* __restrict__ dst)
{
    int i = blockIdx.x * 256 + threadIdx.x;   // 4-elem group, 4M groups
    int e = i << 2;
    const float* src; int off; size_t de;
    if      (e < (1  << 20)) { src = qw; off = e;             de = e; }
    else if (e < (2  << 20)) { src = kw; off = e - (1 << 20); de = e; }
    else if (e < (3  << 20)) { src = vw; off = e - (2 << 20); de = e; }
    else if (e < (4  << 20)) { src = ow; off = e - (3 << 20); de = e; }
    else if (e < (8  << 20)) {
        src = gw; off = e - (4 << 20);
        int chan = off >> 10, col = off & 1023;
        de = (size_t)(4 << 20) + (size_t)(((chan >> 4) << 5) + (chan & 15)) * 1024 + col;
    }
    else if (e < (12 << 20)) {
        src = uw; off = e - (8 << 20);
        int chan = off >> 10, col = off & 1023;
        de = (size_t)(4 << 20) + (size_t)(((chan >> 4) << 5) + 16 + (chan & 15)) * 1024 + col;
    }
    else                     { src = dw; off = e - (12 << 20); de = e; }
    float4 v = *(const float4*)(src + off);
    ushort4 o;
    o.x = f2bf(v.x); o.y = f2bf(v.y); o.z = f2bf(v.z); o.w = f2bf(v.w);
    *(ushort4*)(dst + de) = o;
}

// ---------------- im2col (bf16 out) ----------------
__global__ __launch_bounds__(256) void im2col_kernel(
    const float* __restrict__ img0, const float* __restrict__ img1,
    ushort* __restrict__ P)
{
    int s = blockIdx.x;
    const float* img; int W, ph, pw;
    if (s < S0) { img = img0; W = 512; ph = s >> 5; pw = s & 31; }
    else { int t = s - S0; img = img1; W = 256; ph = t >> 4; pw = t & 15; }
    for (int k = threadIdx.x; k < KCONV; k += 256) {
        int c = k >> 8; int r = k & 255; int y = r >> 4; int x = r & 15;
        P[(size_t)s * KCONV + k] =
            f2bf(img[(size_t)c * 512 * W + (size_t)(ph * 16 + y) * W + (pw * 16 + x)]);
    }
}

// ====== 3-buffer depth-2 K-loop (proven-correct in r5's gemm_gu8), 128^2 tile ======
// One barrier + counted vmcnt per K-step. Steady state: tiles kt..kt+1 in flight,
// wait_vm<NL> drains the oldest (tile kt); final iteration drains fully. Stage of
// kt+2 issued AFTER the barrier into buffer (kt+2)%3, last read at kt-1 (ds_reads
// complete before that barrier -> provably free). Stage lambda shared via macro.
#define STAGE_LAMBDA(NLA_, NLB_)                                                 \
    auto stage = [&](int b, int k0) {                                            \
        _Pragma("unroll")                                                        \
        for (int i_ = 0; i_ < NLA_; ++i_) {                                      \
            int idx = t + i_ * 256;                                              \
            int r_ = idx >> 2, c8_ = (idx & 3) << 3;                             \
            __builtin_amdgcn_global_load_lds(                                    \
                (gvoid*)(A + (size_t)(bm + r_) * K + k0 + c8_),                  \
                (lvoid*)(&As[b][idx * 8]), 16, 0, 0);                            \
        }                                                                        \
        _Pragma("unroll")                                                        \
        for (int i_ = 0; i_ < NLB_; ++i_) {                                      \
            int idx = t + i_ * 256;                                              \
            int r_ = idx >> 2, c8_ = (idx & 3) << 3;                             \
            __builtin_amdgcn_global_load_lds(                                    \
                (gvoid*)(B + (size_t)(bn + r_) * K + k0 + c8_),                  \
                (lvoid*)(&Bs[b][idx * 8]), 16, 0, 0);                            \
        }                                                                        \
    };

#define LOOP3B_HEAD(NL_, KBASE_)                                                 \
    stage(0, KBASE_); stage(1, KBASE_ + 32);                                     \
    int cbuf = 0, sbuf = 2;                                                      \
    for (int kt = 0; kt < NKT; ++kt) {                                           \
        if (kt + 1 < NKT) wait_vm<NL_>(); else wait_vm<0>();                     \
        __builtin_amdgcn_sched_barrier(0);                                       \
        __builtin_amdgcn_s_barrier();                                            \
        __builtin_amdgcn_sched_barrier(0);                                       \
        if (kt + 2 < NKT) {                                                      \
            stage(sbuf, KBASE_ + ((kt + 2) << 5));                               \
            sbuf = (sbuf == 2) ? 0 : sbuf + 1;                                   \
        }

#define LOOP3B_TAIL                                                              \
        cbuf = (cbuf == 2) ? 0 : cbuf + 1;                                       \
    }

// ---------------- generic 3-buf GEMM: C[M][N] = A[M][K] * B[N][K]^T ----------------
template<int BM, int BN, bool OUT_BF16>
__global__ __launch_bounds__(256) void gemm3b(
    const ushort* __restrict__ A, const ushort* __restrict__ B,
    void* __restrict__ Cout, int M, int N, int K)
{
    constexpr int WMT = BM / 32, WNT = BN / 32;
    constexpr int NLA = (BM * 32) / (8 * 256);
    constexpr int NLB = (BN * 32) / (8 * 256);
    constexpr int NL  = NLA + NLB;
    __shared__ ushort As[3][BM * 32];
    __shared__ ushort Bs[3][BN * 32];
    const int t = threadIdx.x;
    const int bm = blockIdx.x * BM, bn = blockIdx.y * BN;
    const int wave = t >> 6, lane = t & 63;
    const int wm = (wave & 1) * (BM / 2), wn = (wave >> 1) * (BN / 2);
    const int frow = lane & 15, fq = lane >> 4;
    STAGE_LAMBDA(NLA, NLB)

    f32x4 acc[WMT][WNT];
    #pragma unroll
    for (int i = 0; i < WMT; ++i)
        #pragma unroll
        for (int j = 0; j < WNT; ++j) acc[i][j] = (f32x4){0.f, 0.f, 0.f, 0.f};

    const int NKT = K >> 5;
    LOOP3B_HEAD(NL, 0)
        bf16x8 af[WMT], bfr[WNT];
        #pragma unroll
        for (int i = 0; i < WMT; ++i)
            af[i] = *(const bf16x8*)(&As[cbuf][(wm + 16 * i + frow) * 32 + fq * 8]);
        #pragma unroll
        for (int j = 0; j < WNT; ++j)
            bfr[j] = *(const bf16x8*)(&Bs[cbuf][(wn + 16 * j + frow) * 32 + fq * 8]);
        __builtin_amdgcn_s_setprio(1);
        #pragma unroll
        for (int i = 0; i < WMT; ++i)
            #pragma unroll
            for (int j = 0; j < WNT; ++j)
                acc[i][j] = __builtin_amdgcn_mfma_f32_16x16x32_bf16(
                    af[i], bfr[j], acc[i][j], 0, 0, 0);
        __builtin_amdgcn_s_setprio(0);
    LOOP3B_TAIL
    #pragma unroll
    for (int i = 0; i < WMT; ++i) {
        #pragma unroll
        for (int j = 0; j < WNT; ++j) {
            #pragma unroll
            for (int r = 0; r < 4; ++r) {
                int row = bm + wm + 16 * i + fq * 4 + r;
                int col = bn + wn + 16 * j + frow;
                float vv = acc[i][j][r];
                if (OUT_BF16) ((ushort*)Cout)[(size_t)row * N + col] = f2bf(vv);
                else          ((float*)Cout)[(size_t)row * N + col] = vv;
            }
        }
    }
}

// ------- qkv GEMM (128x128, 3-buf) with fused RoPE + direct-V^T epilogue -------
// cols [0,2048): rope'd bf16 -> qkb; cols [2048,3072): bf16 -> vT[head][d][s]
// directly (8B per (i,j) store; drops the separate vtrans pass).
__global__ __launch_bounds__(256) void gemm3b_qkv(
    const ushort* __restrict__ A, const ushort* __restrict__ B,
    ushort* __restrict__ qkb, ushort* __restrict__ vT,
    const float* __restrict__ cs, const float* __restrict__ sn, int K)
{
    constexpr int BM = 128, BN = 128;
    __shared__ ushort As[3][BM * 32];
    __shared__ ushort Bs[3][BN * 32];
    const int t = threadIdx.x;
    const int bm = blockIdx.x * BM, bn = blockIdx.y * BN;
    const int wave = t >> 6, lane = t & 63;
    const int wm = (wave & 1) * 64, wn = (wave >> 1) * 64;
    const int frow = lane & 15, fq = lane >> 4;
    STAGE_LAMBDA(2, 2)

    f32x4 acc[4][4];
    #pragma unroll
    for (int i = 0; i < 4; ++i)
        #pragma unroll
        for (int j = 0; j < 4; ++j) acc[i][j] = (f32x4){0.f, 0.f, 0.f, 0.f};

    const int NKT = K >> 5;
    LOOP3B_HEAD(4, 0)
        bf16x8 af[4], bfr[4];
        #pragma unroll
        for (int i = 0; i < 4; ++i)
            af[i] = *(const bf16x8*)(&As[cbuf][(wm + 16 * i + frow) * 32 + fq * 8]);
        #pragma unroll
        for (int j = 0; j < 4; ++j)
            bfr[j] = *(const bf16x8*)(&Bs[cbuf][(wn + 16 * j + frow) * 32 + fq * 8]);
        __builtin_amdgcn_s_setprio(1);
        #pragma unroll
        for (int i = 0; i < 4; ++i)
            #pragma unroll
            for (int j = 0; j < 4; ++j)
                acc[i][j] = __builtin_amdgcn_mfma_f32_16x16x32_bf16(
                    af[i], bfr[j], acc[i][j], 0, 0, 0);
        __builtin_amdgcn_s_setprio(0);
    LOOP3B_TAIL
    const int colbase = bn + wn;          // 64-aligned; section uniform per wave-half
    const int part = colbase >> 10;       // 0=q, 1=k, 2=v
    if (part < 2) {
        #pragma unroll
        for (int i = 0; i < 4; ++i) {
            #pragma unroll
            for (int r = 0; r < 4; ++r) {
                int row = bm + wm + 16 * i + fq * 4 + r;
                float cv0 = cs[row * 32 + frow],      sv0 = sn[row * 32 + frow];
                float cv1 = cs[row * 32 + 16 + frow], sv1 = sn[row * 32 + 16 + frow];
                float xa0 = acc[i][0][r], xa1 = acc[i][1][r];
                float xb0 = acc[i][2][r], xb1 = acc[i][3][r];
                ushort* dst = qkb + (size_t)row * QKS + (part << 10) + (colbase & 1023) + frow;
                dst[0]  = f2bf(xa0 * cv0 - xb0 * sv0);
                dst[16] = f2bf(xa1 * cv1 - xb1 * sv1);
                dst[32] = f2bf(xb0 * cv0 + xa0 * sv0);
                dst[48] = f2bf(xb1 * cv1 + xa1 * sv1);
            }
        }
    } else {
        const int hh = (colbase - 2048) >> 6;   // head (wave-uniform)
        #pragma unroll
        for (int i = 0; i < 4; ++i) {
            int row = bm + wm + 16 * i + (fq << 2);
            #pragma unroll
            for (int j = 0; j < 4; ++j) {
                int d = 16 * j + frow;
                ushort4 o4;
                o4.x = f2bf(acc[i][j][0]); o4.y = f2bf(acc[i][j][1]);
                o4.z = f2bf(acc[i][j][2]); o4.w = f2bf(acc[i][j][3]);
                *(ushort4*)(vT + ((size_t)hh * HD + d) * S_TOT + row) = o4;
            }
        }
    }
}

// ------- gate/up GEMM (128x128, 3-buf, gu-interleaved weights) + fused SiLU -------
__global__ __launch_bounds__(256) void gemm3b_gu(
    const ushort* __restrict__ A, const ushort* __restrict__ B,
    ushort* __restrict__ gb, int K)
{
    constexpr int BM = 128, BN = 128;
    __shared__ ushort As[3][BM * 32];
    __shared__ ushort Bs[3][BN * 32];
    const int t = threadIdx.x;
    const int bm = blockIdx.x * BM, bn = blockIdx.y * BN;
    const int wave = t >> 6, lane = t & 63;
    const int wm = (wave & 1) * 64, wn = (wave >> 1) * 64;
    const int frow = lane & 15, fq = lane >> 4;
    STAGE_LAMBDA(2, 2)

    f32x4 acc[4][4];
    #pragma unroll
    for (int i = 0; i < 4; ++i)
        #pragma unroll
        for (int j = 0; j < 4; ++j) acc[i][j] = (f32x4){0.f, 0.f, 0.f, 0.f};

    const int NKT = K >> 5;
    LOOP3B_HEAD(4, 0)
        bf16x8 af[4], bfr[4];
        #pragma unroll
        for (int i = 0; i < 4; ++i)
            af[i] = *(const bf16x8*)(&As[cbuf][(wm + 16 * i + frow) * 32 + fq * 8]);
        #pragma unroll
        for (int j = 0; j < 4; ++j)
            bfr[j] = *(const bf16x8*)(&Bs[cbuf][(wn + 16 * j + frow) * 32 + fq * 8]);
        __builtin_amdgcn_s_setprio(1);
        #pragma unroll
        for (int i = 0; i < 4; ++i)
            #pragma unroll
            for (int j = 0; j < 4; ++j)
                acc[i][j] = __builtin_amdgcn_mfma_f32_16x16x32_bf16(
                    af[i], bfr[j], acc[i][j], 0, 0, 0);
        __builtin_amdgcn_s_setprio(0);
    LOOP3B_TAIL
    // fused SiLU: abs 16-col block even = gate, odd = up of same channels (same lane)
    #pragma unroll
    for (int i = 0; i < 4; ++i) {
        #pragma unroll
        for (int p = 0; p < 2; ++p) {
            int chan = ((bn + wn) >> 1) + p * 16 + frow;
            #pragma unroll
            for (int r = 0; r < 4; ++r) {
                int row = bm + wm + 16 * i + fq * 4 + r;
                float g = acc[i][2 * p][r], u = acc[i][2 * p + 1][r];
                float sg = 1.f / (1.f + __expf(-g));
                gb[(size_t)row * INTER + chan] = f2bf(g * sg * u);
            }
        }
    }
}

// ------- 3-buf split-K GEMM: writes f32 partial slabs (no atomics) -------
template<int SPLITK>
__global__ __launch_bounds__(256) void gemm3b_sk(
    const ushort* __restrict__ A, const ushort* __restrict__ B,
    float* __restrict__ P, int M, int N, int K)
{
    constexpr int BM = 128, BN = 128;
    __shared__ ushort As[3][BM * 32];
    __shared__ ushort Bs[3][BN * 32];
    const int t = threadIdx.x;
    const int bm = blockIdx.x * BM, bn = blockIdx.y * BN;
    const int kc = K / SPLITK;
    const int kb = blockIdx.z * kc;
    const int wave = t >> 6, lane = t & 63;
    const int wm = (wave & 1) * 64, wn = (wave >> 1) * 64;
    const int frow = lane & 15, fq = lane >> 4;
    STAGE_LAMBDA(2, 2)

    f32x4 acc[4][4];
    #pragma unroll
    for (int i = 0; i < 4; ++i)
        #pragma unroll
        for (int j = 0; j < 4; ++j) acc[i][j] = (f32x4){0.f, 0.f, 0.f, 0.f};

    const int NKT = kc >> 5;
    LOOP3B_HEAD(4, kb)
        bf16x8 af[4], bfr[4];
        #pragma unroll
        for (int i = 0; i < 4; ++i)
            af[i] = *(const bf16x8*)(&As[cbuf][(wm + 16 * i + frow) * 32 + fq * 8]);
        #pragma unroll
        for (int j = 0; j < 4; ++j)
            bfr[j] = *(const bf16x8*)(&Bs[cbuf][(wn + 16 * j + frow) * 32 + fq * 8]);
        __builtin_amdgcn_s_setprio(1);
        #pragma unroll
        for (int i = 0; i < 4; ++i)
            #pragma unroll
            for (int j = 0; j < 4; ++j)
                acc[i][j] = __builtin_amdgcn_mfma_f32_16x16x32_bf16(
                    af[i], bfr[j], acc[i][j], 0, 0, 0);
        __builtin_amdgcn_s_setprio(0);
    LOOP3B_TAIL
    float* Pz = P + (size_t)blockIdx.z * M * N;
    #pragma unroll
    for (int i = 0; i < 4; ++i) {
        #pragma unroll
        for (int j = 0; j < 4; ++j) {
            #pragma unroll
            for (int r = 0; r < 4; ++r) {
                int row = bm + wm + 16 * i + fq * 4 + r;
                int col = bn + wn + 16 * j + frow;
                Pz[(size_t)row * N + col] = acc[i][j][r];
            }
        }
    }
}

// x[i] += P0[i] + P1[i] + P2[i] + P3[i]  (float4 vectorized; n4 = n/4)
__global__ __launch_bounds__(256) void reduce4_kernel(
    const float* __restrict__ P, float* __restrict__ x, int n4)
{
    int i = blockIdx.x * 256 + threadIdx.x;
    if (i >= n4) return;
    const int n = n4 << 2;
    float4 a  = ((const float4*)x)[i];
    float4 p0 = ((const float4*)P)[i];
    float4 p1 = ((const float4*)(P + (size_t)n))[i];
    float4 p2 = ((const float4*)(P + (size_t)2 * n))[i];
    float4 p3 = ((const float4*)(P + (size_t)3 * n))[i];
    a.x += p0.x + p1.x + p2.x + p3.x;
    a.y += p0.y + p1.y + p2.y + p3.y;
    a.z += p0.z + p1.z + p2.z + p3.z;
    a.w += p0.w + p1.w + p2.w + p3.w;
    ((float4*)x)[i] = a;
}

// fused: x += sum(4 partials); hnb = rms(x)*w   (one block per row)
__global__ __launch_bounds__(256) void reduce_rms_bf_kernel(
    const float* __restrict__ P, float* __restrict__ x,
    const float* __restrict__ w, ushort* __restrict__ out)
{
    int row = blockIdx.x, t = threadIdx.x;
    size_t off = (size_t)row * HID + t * 4;
    float4 a = *(const float4*)(x + off);
    #pragma unroll
    for (int z = 0; z < 4; ++z) {
        float4 p = *(const float4*)(P + (size_t)z * S_TOT * HID + off);
        a.x += p.x; a.y += p.y; a.z += p.z; a.w += p.w;
    }
    *(float4*)(x + off) = a;
    float ss = a.x * a.x + a.y * a.y + a.z * a.z + a.w * a.w;
    #pragma unroll
    for (int o = 32; o > 0; o >>= 1) ss += __shfl_down(ss, o, 64);
    __shared__ float red[4];
    int wid = t >> 6;
    if ((t & 63) == 0) red[wid] = ss;
    __syncthreads();
    if (t == 0)
        red[0] = rsqrtf((red[0] + red[1] + red[2] + red[3]) / HID + EPSV);
    __syncthreads();
    float rs = red[0];
    const float* wp = w + t * 4;
    ushort4 o4;
    o4.x = f2bf(a.x * rs * wp[0]); o4.y = f2bf(a.y * rs * wp[1]);
    o4.z = f2bf(a.z * rs * wp[2]); o4.w = f2bf(a.w * rs * wp[3]);
    *(ushort4*)(out + off) = o4;
}

// ---------------- RMS norm fp32->fp32 ----------------
__global__ __launch_bounds__(256) void rms_kernel(
    const float* __restrict__ in, const float* __restrict__ w,
    float* __restrict__ out)
{
    int row = blockIdx.x;
    const float* xr = in + (size_t)row * HID;
    float ss = 0.f;
    for (int i = threadIdx.x; i < HID; i += 256) { float v = xr[i]; ss += v * v; }
    #pragma unroll
    for (int off = 32; off > 0; off >>= 1) ss += __shfl_down(ss, off, 64);
    __shared__ float red[4];
    int wid = threadIdx.x >> 6;
    if ((threadIdx.x & 63) == 0) red[wid] = ss;
    __syncthreads();
    if (threadIdx.x == 0)
        red[0] = rsqrtf((red[0] + red[1] + red[2] + red[3]) / HID + EPSV);
    __syncthreads();
    float rs = red[0];
    for (int i = threadIdx.x; i < HID; i += 256)
        out[(size_t)row * HID + i] = xr[i] * rs * w[i];
}

// ---------------- RMS norm fp32->bf16 ----------------
__global__ __launch_bounds__(256) void rms_bf_kernel(
    const float* __restrict__ in, const float* __restrict__ w,
    ushort* __restrict__ out)
{
    int row = blockIdx.x;
    const float* xr = in + (size_t)row * HID;
    float ss = 0.f;
    for (int i = threadIdx.x; i < HID; i += 256) { float v = xr[i]; ss += v * v; }
    #pragma unroll
    for (int off = 32; off > 0; off >>= 1) ss += __shfl_down(ss, off, 64);
    __shared__ float red[4];
    int wid = threadIdx.x >> 6;
    if ((threadIdx.x & 63) == 0) red[wid] = ss;
    __syncthreads();
    if (threadIdx.x == 0)
        red[0] = rsqrtf((red[0] + red[1] + red[2] + red[3]) / HID + EPSV);
    __syncthreads();
    float rs = red[0];
    for (int i = threadIdx.x; i < HID; i += 256)
        out[(size_t)row * HID + i] = f2bf(xr[i] * rs * w[i]);
}

// ---------------- RoPE tables ----------------
__global__ void rope_tab_kernel(float* __restrict__ cs, float* __restrict__ sn)
{
    int s = blockIdx.x; int j = threadIdx.x; // 32 threads
    int h, w;
    if (s < S0) { h = s >> 5; w = s & 31; }
    else { int t = s - S0; h = t >> 4; w = t & 15; }
    float f;
    if (j < 16) f = (float)h * powf(10000.f, -(4.f * j) / 64.f);
    else        f = (float)w * powf(10000.f, -(4.f * (j - 16) + 2.f) / 64.f);
    cs[s * 32 + j] = cosf(f);
    sn[s * 32 + j] = sinf(f);
}

// ---------------- MFMA flash attention ----------------
__global__ __launch_bounds__(256) void flash_mfma_kernel(
    const ushort* __restrict__ qkb, const ushort* __restrict__ vT,
    ushort* __restrict__ o)
{
    __shared__ ushort Ks[64 * 72];
    __shared__ ushort Vt[64 * 72];
    __shared__ ushort Ps[4 * 16 * 72];
    int tile = blockIdx.x;
    int hh = blockIdx.y;
    int segStart, q0, nkt;
    if (tile < 16) { segStart = 0; q0 = tile << 6; nkt = 16; }
    else { segStart = S0; q0 = S0 + ((tile - 16) << 6); nkt = 8; }
    const int t = threadIdx.x;
    const int wave = t >> 6, lane = t & 63;
    const int c = lane & 15, fq = lane >> 4;
    const int wq = wave << 4;
    ushort* Pw = Ps + wave * 16 * 72;

    bf16x8 qf[2];
    #pragma unroll
    for (int ks = 0; ks < 2; ++ks)
        qf[ks] = *(const bf16x8*)(qkb + (size_t)(q0 + wq + c) * QKS + hh * HD + ks * 32 + fq * 8);

    float m_i[4], l_i[4];
    f32x4 accO[4];
    #pragma unroll
    for (int r = 0; r < 4; ++r) { m_i[r] = -1e30f; l_i[r] = 0.f; }
    #pragma unroll
    for (int nt = 0; nt < 4; ++nt) accO[nt] = (f32x4){0.f, 0.f, 0.f, 0.f};

    for (int kt = 0; kt < nkt; ++kt) {
        int kbase = segStart + (kt << 6);
        __syncthreads();
        #pragma unroll
        for (int i = 0; i < 2; ++i) {
            int u = t + (i << 8);
            int r = u >> 3, c8 = (u & 7) << 3;
            u16x8 kv = *(const u16x8*)(qkb + (size_t)(kbase + r) * QKS + 1024 + hh * HD + c8);
            *(u16x8*)(Ks + r * 72 + c8) = kv;
            u16x8 vv = *(const u16x8*)(vT + ((size_t)hh * HD + r) * S_TOT + kbase + c8);
            *(u16x8*)(Vt + r * 72 + c8) = vv;
        }
        __syncthreads();

        f32x4 acc[4];
        #pragma unroll
        for (int nt = 0; nt < 4; ++nt) acc[nt] = (f32x4){0.f, 0.f, 0.f, 0.f};
        #pragma unroll
        for (int ks = 0; ks < 2; ++ks) {
            #pragma unroll
            for (int nt = 0; nt < 4; ++nt) {
                bf16x8 bfr = *(const bf16x8*)(Ks + (nt * 16 + c) * 72 + ks * 32 + fq * 8);
                acc[nt] = __builtin_amdgcn_mfma_f32_16x16x32_bf16(qf[ks], bfr, acc[nt], 0, 0, 0);
            }
        }

        #pragma unroll
        for (int r = 0; r < 4; ++r) {
            float s0v = acc[0][r] * SCALEV, s1v = acc[1][r] * SCALEV;
            float s2v = acc[2][r] * SCALEV, s3v = acc[3][r] * SCALEV;
            float rm = fmaxf(fmaxf(s0v, s1v), fmaxf(s2v, s3v));
            #pragma unroll
            for (int msk = 1; msk < 16; msk <<= 1)
                rm = fmaxf(rm, __shfl_xor(rm, msk, 64));
            float mn = fmaxf(m_i[r], rm);
            float al = __expf(m_i[r] - mn);
            float p0 = __expf(s0v - mn), p1 = __expf(s1v - mn);
            float p2 = __expf(s2v - mn), p3 = __expf(s3v - mn);
            float rs = p0 + p1 + p2 + p3;
            #pragma unroll
            for (int msk = 1; msk < 16; msk <<= 1)
                rs += __shfl_xor(rs, msk, 64);
            l_i[r] = l_i[r] * al + rs;
            m_i[r] = mn;
            #pragma unroll
            for (int nt = 0; nt < 4; ++nt) accO[nt][r] *= al;
            int qrow = (fq << 2) + r;
            Pw[qrow * 72 + 0  + c] = f2bf(p0);
            Pw[qrow * 72 + 16 + c] = f2bf(p1);
            Pw[qrow * 72 + 32 + c] = f2bf(p2);
            Pw[qrow * 72 + 48 + c] = f2bf(p3);
        }

        #pragma unroll
        for (int ks = 0; ks < 2; ++ks) {
            bf16x8 pa = *(const bf16x8*)(Pw + c * 72 + ks * 32 + fq * 8);
            #pragma unroll
            for (int nt = 0; nt < 4; ++nt) {
                bf16x8 bv = *(const bf16x8*)(Vt + (nt * 16 + c) * 72 + ks * 32 + fq * 8);
                accO[nt] = __builtin_amdgcn_mfma_f32_16x16x32_bf16(pa, bv, accO[nt], 0, 0, 0);
            }
        }
    }

    #pragma unroll
    for (int r = 0; r < 4; ++r) {
        float inv = 1.f / l_i[r];
        int row = q0 + wq + (fq << 2) + r;
        #pragma unroll
        for (int nt = 0; nt < 4; ++nt)
            o[(size_t)row * HID + hh * HD + nt * 16 + c] = f2bf(accO[nt][r] * inv);
    }
}

// ---------------- copy to out ----------------
__global__ __launch_bounds__(256) void copy_kernel(
    const float* __restrict__ src, float* __restrict__ dst, int n)
{
    int i = blockIdx.x * 256 + threadIdx.x;
    if (i < n) dst[i] = src[i];
}

extern "C" void kernel_launch(void* const* d_in, const int* in_sizes, int n_in,
                              void* d_out, int out_size, void* d_ws, size_t ws_size,
                              hipStream_t stream)
{
    const float* img0        = (const float*)d_in[0];
    const float* img1        = (const float*)d_in[1];
    const float* conv_w      = (const float*)d_in[2];
    const float* ln_pre_w    = (const float*)d_in[3];
    const float* attn_norm_w = (const float*)d_in[4];
    const float* q_w         = (const float*)d_in[5];
    const float* k_w         = (const float*)d_in[6];
    const float* v_w         = (const float*)d_in[7];
    const float* o_w         = (const float*)d_in[8];
    const float* ffn_norm_w  = (const float*)d_in[9];
    const float* gate_w      = (const float*)d_in[10];
    const float* up_w        = (const float*)d_in[11];
    const float* down_w      = (const float*)d_in[12];

    char* p = (char*)d_ws;
    float* x    = (float*)p;   p += (size_t)1572864 * 4;   // [1536][1024]
    float* cs   = (float*)p;   p += (size_t)49152 * 4;
    float* sn   = (float*)p;   p += (size_t)49152 * 4;
    ushort* qkb = (ushort*)p;  p += (size_t)3145728 * 2;   // [1536][2048] rope'd q|k bf16
    ushort* vTb = (ushort*)p;  p += (size_t)1572864 * 2;   // [16][64][1536] V^T bf16
    ushort* hnb = (ushort*)p;  p += (size_t)1572864 * 2;   // [1536][1024]
    ushort* obb = (ushort*)p;  p += (size_t)1572864 * 2;   // [1536][1024]
    ushort* gb  = (ushort*)p;  p += (size_t)6291456 * 2;   // [1536][4096] silu(g)*u bf16
    float* skP  = (float*)p;   p += (size_t)6291456 * 4;   // 4 x [1536][1024] f32 partials
    ushort* Pb  = (ushort*)p;  p += (size_t)1179648 * 2;   // [1536][768]
    ushort* cvb = (ushort*)p;  p += (size_t)786432 * 2;    // conv_w bf16
    ushort* wbuf= (ushort*)p;  p += (size_t)16777216 * 2;  // per-layer weights

    ushort* wqkv = wbuf;                 // [3072][1024]
    ushort* wo   = wbuf + 3145728;       // [1024][1024]
    ushort* wgu  = wbuf + 4194304;       // [8192][1024] gu-interleaved
    ushort* wdn  = wbuf + 12582912;      // [1024][4096]

    dim3 blk(256);

    cvt_kernel<<<768, blk, 0, stream>>>(conv_w, cvb, 786432 / 4);
    im2col_kernel<<<S_TOT, blk, 0, stream>>>(img0, img1, Pb);
    gemm3b<64, 64, false><<<dim3(24, 16), blk, 0, stream>>>(
        Pb, cvb, x, S_TOT, HID, KCONV);
    rms_kernel<<<S_TOT, blk, 0, stream>>>(x, ln_pre_w, x);
    rope_tab_kernel<<<S_TOT, 32, 0, stream>>>(cs, sn);

    for (int l = 0; l < NLAYERS; ++l) {
        cvt_layer_kernel<<<16384, blk, 0, stream>>>(
            q_w + (size_t)l * 1048576, k_w + (size_t)l * 1048576,
            v_w + (size_t)l * 1048576, o_w + (size_t)l * 1048576,
            gate_w + (size_t)l * 4194304, up_w + (size_t)l * 4194304,
            down_w + (size_t)l * 4194304, wbuf);

        rms_bf_kernel<<<S_TOT, blk, 0, stream>>>(x, attn_norm_w + (size_t)l * HID, hnb);
        // qkv GEMM: fused RoPE (q,k -> qkb) + direct V^T write (v -> vTb)
        gemm3b_qkv<<<dim3(12, 24), blk, 0, stream>>>(
            hnb, wqkv, qkb, vTb, cs, sn, HID);
        flash_mfma_kernel<<<dim3(24, HEADS), blk, 0, stream>>>(qkb, vTb, obb);
        // o-projection: split-K partials, then fused (x += sum) + rms -> hnb
        gemm3b_sk<4><<<dim3(12, 8, 4), blk, 0, stream>>>(
            obb, wo, skP, S_TOT, HID, HID);
        reduce_rms_bf_kernel<<<S_TOT, blk, 0, stream>>>(
            skP, x, ffn_norm_w + (size_t)l * HID, hnb);
        // gate/up GEMM: 128^2 3-buf deep pipeline, fused SiLU -> gb bf16
        gemm3b_gu<<<dim3(12, 64), blk, 0, stream>>>(hnb, wgu, gb, HID);
        // down-projection: split-K=4 partials + reduce
        gemm3b_sk<4><<<dim3(12, 8, 4), blk, 0, stream>>>(
            gb, wdn, skP, S_TOT, HID, INTER);
        reduce4_kernel<<<1536, blk, 0, stream>>>(skP, x, S_TOT * HID / 4);
    }
    copy_kernel<<<(S_TOT * HID) / 256, blk, 0, stream>>>(x, (float*)d_out, S_TOT * HID);
}

// Round 7
// 902.842 us; speedup vs baseline: 1.0628x; 1.0177x over previous
//
#include <hip/hip_runtime.h>
#include <hip/hip_bf16.h>
#include <math.h>

#define S_TOT 1536
#define S0    1024
#define HID   1024
#define HEADS 16
#define HD    64
#define INTER 4096
#define NLAYERS 4
#define KCONV 768
#define EPSV  1e-5f
#define SCALEV 0.125f
#define QKS   2048   // fused rope'd q|k bf16 row stride

typedef __attribute__((ext_vector_type(8))) __bf16 bf16x8;
typedef __attribute__((ext_vector_type(8))) unsigned short u16x8;
typedef __attribute__((ext_vector_type(4))) float f32x4;
typedef __attribute__((address_space(1))) void gvoid;
typedef __attribute__((address_space(3))) void lvoid;

__device__ __forceinline__ ushort f2bf(float f) {
    union { float f; unsigned u; } v; v.f = f;
    unsigned u = v.u;
    return (ushort)((u + 0x7FFFu + ((u >> 16) & 1u)) >> 16);
}
__device__ __forceinline__ float bf2f(ushort b) {
    union { unsigned u; float f; } v; v.u = ((unsigned)b) << 16;
    return v.f;
}

// counted vmcnt wait with compile-time immediate
template<int N> __device__ __forceinline__ void wait_vm() {
    if constexpr (N == 0)      asm volatile("s_waitcnt vmcnt(0)" ::: "memory");
    else if constexpr (N == 2) asm volatile("s_waitcnt vmcnt(2)" ::: "memory");
    else if constexpr (N == 4) asm volatile("s_waitcnt vmcnt(4)" ::: "memory");
    else if constexpr (N == 8) asm volatile("s_waitcnt vmcnt(8)" ::: "memory");
    else                       asm volatile("s_waitcnt vmcnt(0)" ::: "memory");
}

// ---------------- weight converts ----------------
__global__ __launch_bounds__(256) void cvt_kernel(
    const float* __restrict__ src, ushort* __restrict__ dst, int n4)
{
    int i = blockIdx.x * 256 + threadIdx.x;
    if (i < n4) {
        float4 v = ((const float4*)src)[i];
        ushort4 o;
        o.x = f2bf(v.x); o.y = f2bf(v.y); o.z = f2bf(v.z); o.w = f2bf(v.w);
        ((ushort4*)dst)[i] = o;
    }
}

// fused per-layer weight convert: dst = [qkv(3M) | o(1M) | gu-interleaved(8M) | down(4M)]
// gate/up rows interleaved in 16-row blocks so (gate[c], up[c]) are same-lane in C-frag.
__global__ __launch_bounds__(256) void cvt_layer_kernel(
    const float* __restrict__ qw, const float* __restrict__ kw,
    const float* __restrict__ vw, const float* __restrict__ ow,
    const float* __restrict__ gw, const float* __restrict__ uw,
    const float* __restrict__ dw, ushort* __restrict__ dst)
{
    int i = blockIdx.x * 256 + threadIdx.x;   // 4-elem group, 4M groups
    int e = i << 2;
    const float* src; int off; size_t de;
    if      (e < (1  << 20)) { src = qw; off = e;             de = e; }
    else if (e < (2  << 20)) { src = kw; off = e - (1 << 20); de = e; }
    else if (e < (3  << 20)) { src = vw; off = e - (2 << 20); de = e; }
    else if (e < (4  << 20)) { src = ow; off = e - (3 << 20); de = e; }
    else if (e < (8  << 20)) {
        src = gw; off = e - (4 << 20);
        int chan = off >> 10, col = off & 1023;
        de = (size_t)(4 << 20) + (size_t)(((chan >> 4) << 5) + (chan & 15)) * 1024 + col;
    }
    else if (e < (12 << 20)) {
        src = uw; off = e - (8 << 20);
        int chan = off >> 10, col = off & 1023;
        de = (size_t)(4 << 20) + (size_t)(((chan >> 4) << 5) + 16 + (chan & 15)) * 1024 + col;
    }
    else                     { src = dw; off = e - (12 << 20); de = e; }
    float4 v = *(const float4*)(src + off);
    ushort4 o;
    o.x = f2bf(v.x); o.y = f2bf(v.y); o.z = f2bf(v.z); o.w = f2bf(v.w);
    *(ushort4*)(dst + de) = o;
}

// ---------------- im2col (bf16 out) ----------------
__global__ __launch_bounds__(256) void im2col_kernel(
    const float* __restrict__ img0, const float* __restrict__ img1,
    ushort* __restrict__ P)
{
    int s = blockIdx.x;
    const float* img; int W, ph, pw;
    if (s < S0) { img = img0; W = 512; ph = s >> 5; pw = s & 31; }
    else { int t = s - S0; img = img1; W = 256; ph = t >> 4; pw = t & 15; }
    for (int k = threadIdx.x; k < KCONV; k += 256) {
        int c = k >> 8; int r = k & 255; int y = r >> 4; int x = r & 15;
        P[(size_t)s * KCONV + k] =
            f2bf(img[(size_t)c * 512 * W + (size_t)(ph * 16 + y) * W + (pw * 16 + x)]);
    }
}

// ====== 3-buffer depth-2 K-loop, 128^2 tile, T2 XOR bank swizzle ======
// One barrier + counted vmcnt per K-step (r5/r6-proven). Bank-conflict fix
// (r6 PMC: 3.1M conflict cycles, 8-way on ds_read_b128): logical 16B-slot lc
// of each row stored at phys slot lc^(row&3). Both-sides rule (r5-proven):
// linear gload_lds DEST + inverse-swizzled GLOBAL source + swizzled ds_read.
// Spreads a 16-lane fragment read over 8 banks -> 2-way (free, m136).
#define STAGE_LAMBDA(NLA_, NLB_)                                                 \
    auto stage = [&](int b, int k0) {                                            \
        _Pragma("unroll")                                                        \
        for (int i_ = 0; i_ < NLA_; ++i_) {                                      \
            int idx = t + i_ * 256;                                              \
            int r_ = idx >> 2, sp_ = idx & 3;                                    \
            int lc_ = sp_ ^ (r_ & 3);                                            \
            __builtin_amdgcn_global_load_lds(                                    \
                (gvoid*)(A + (size_t)(bm + r_) * K + k0 + (lc_ << 3)),           \
                (lvoid*)(&As[b][idx * 8]), 16, 0, 0);                            \
        }                                                                        \
        _Pragma("unroll")                                                        \
        for (int i_ = 0; i_ < NLB_; ++i_) {                                      \
            int idx = t + i_ * 256;                                              \
            int r_ = idx >> 2, sp_ = idx & 3;                                    \
            int lc_ = sp_ ^ (r_ & 3);                                            \
            __builtin_amdgcn_global_load_lds(                                    \
                (gvoid*)(B + (size_t)(bn + r_) * K + k0 + (lc_ << 3)),           \
                (lvoid*)(&Bs[b][idx * 8]), 16, 0, 0);                            \
        }                                                                        \
    };

#define LOOP3B_HEAD(NL_, KBASE_)                                                 \
    stage(0, KBASE_); stage(1, KBASE_ + 32);                                     \
    int cbuf = 0, sbuf = 2;                                                      \
    for (int kt = 0; kt < NKT; ++kt) {                                           \
        if (kt + 1 < NKT) wait_vm<NL_>(); else wait_vm<0>();                     \
        __builtin_amdgcn_sched_barrier(0);                                       \
        __builtin_amdgcn_s_barrier();                                            \
        __builtin_amdgcn_sched_barrier(0);                                       \
        if (kt + 2 < NKT) {                                                      \
            stage(sbuf, KBASE_ + ((kt + 2) << 5));                               \
            sbuf = (sbuf == 2) ? 0 : sbuf + 1;                                   \
        }

#define LOOP3B_TAIL                                                              \
        cbuf = (cbuf == 2) ? 0 : cbuf + 1;                                       \
    }

// swizzled fragment read: row's 16B slot fq stored at fq^(row&3)
#define LDS_A(i_) (*(const bf16x8*)(&As[cbuf][((wm + 16 * (i_) + frow) << 5) + \
                     ((fq ^ ((wm + 16 * (i_) + frow) & 3)) << 3)]))
#define LDS_B(j_) (*(const bf16x8*)(&Bs[cbuf][((wn + 16 * (j_) + frow) << 5) + \
                     ((fq ^ ((wn + 16 * (j_) + frow) & 3)) << 3)]))

// ---------------- generic 3-buf GEMM: C[M][N] = A[M][K] * B[N][K]^T ----------------
template<int BM, int BN, bool OUT_BF16>
__global__ __launch_bounds__(256) void gemm3b(
    const ushort* __restrict__ A, const ushort* __restrict__ B,
    void* __restrict__ Cout, int M, int N, int K)
{
    constexpr int WMT = BM / 32, WNT = BN / 32;
    constexpr int NLA = (BM * 32) / (8 * 256);
    constexpr int NLB = (BN * 32) / (8 * 256);
    constexpr int NL  = NLA + NLB;
    __shared__ ushort As[3][BM * 32];
    __shared__ ushort Bs[3][BN * 32];
    const int t = threadIdx.x;
    const int bm = blockIdx.x * BM, bn = blockIdx.y * BN;
    const int wave = t >> 6, lane = t & 63;
    const int wm = (wave & 1) * (BM / 2), wn = (wave >> 1) * (BN / 2);
    const int frow = lane & 15, fq = lane >> 4;
    STAGE_LAMBDA(NLA, NLB)

    f32x4 acc[WMT][WNT];
    #pragma unroll
    for (int i = 0; i < WMT; ++i)
        #pragma unroll
        for (int j = 0; j < WNT; ++j) acc[i][j] = (f32x4){0.f, 0.f, 0.f, 0.f};

    const int NKT = K >> 5;
    LOOP3B_HEAD(NL, 0)
        bf16x8 af[WMT], bfr[WNT];
        #pragma unroll
        for (int i = 0; i < WMT; ++i) af[i] = LDS_A(i);
        #pragma unroll
        for (int j = 0; j < WNT; ++j) bfr[j] = LDS_B(j);
        __builtin_amdgcn_s_setprio(1);
        #pragma unroll
        for (int i = 0; i < WMT; ++i)
            #pragma unroll
            for (int j = 0; j < WNT; ++j)
                acc[i][j] = __builtin_amdgcn_mfma_f32_16x16x32_bf16(
                    af[i], bfr[j], acc[i][j], 0, 0, 0);
        __builtin_amdgcn_s_setprio(0);
    LOOP3B_TAIL
    #pragma unroll
    for (int i = 0; i < WMT; ++i) {
        #pragma unroll
        for (int j = 0; j < WNT; ++j) {
            #pragma unroll
            for (int r = 0; r < 4; ++r) {
                int row = bm + wm + 16 * i + fq * 4 + r;
                int col = bn + wn + 16 * j + frow;
                float vv = acc[i][j][r];
                if (OUT_BF16) ((ushort*)Cout)[(size_t)row * N + col] = f2bf(vv);
                else          ((float*)Cout)[(size_t)row * N + col] = vv;
            }
        }
    }
}

// ------- qkv GEMM (128x128, 3-buf, swizzled) with fused RoPE + direct-V^T epilogue -------
__global__ __launch_bounds__(256) void gemm3b_qkv(
    const ushort* __restrict__ A, const ushort* __restrict__ B,
    ushort* __restrict__ qkb, ushort* __restrict__ vT,
    const float* __restrict__ cs, const float* __restrict__ sn, int K)
{
    constexpr int BM = 128, BN = 128;
    __shared__ ushort As[3][BM * 32];
    __shared__ ushort Bs[3][BN * 32];
    const int t = threadIdx.x;
    const int bm = blockIdx.x * BM, bn = blockIdx.y * BN;
    const int wave = t >> 6, lane = t & 63;
    const int wm = (wave & 1) * 64, wn = (wave >> 1) * 64;
    const int frow = lane & 15, fq = lane >> 4;
    STAGE_LAMBDA(2, 2)

    f32x4 acc[4][4];
    #pragma unroll
    for (int i = 0; i < 4; ++i)
        #pragma unroll
        for (int j = 0; j < 4; ++j) acc[i][j] = (f32x4){0.f, 0.f, 0.f, 0.f};

    const int NKT = K >> 5;
    LOOP3B_HEAD(4, 0)
        bf16x8 af[4], bfr[4];
        #pragma unroll
        for (int i = 0; i < 4; ++i) af[i] = LDS_A(i);
        #pragma unroll
        for (int j = 0; j < 4; ++j) bfr[j] = LDS_B(j);
        __builtin_amdgcn_s_setprio(1);
        #pragma unroll
        for (int i = 0; i < 4; ++i)
            #pragma unroll
            for (int j = 0; j < 4; ++j)
                acc[i][j] = __builtin_amdgcn_mfma_f32_16x16x32_bf16(
                    af[i], bfr[j], acc[i][j], 0, 0, 0);
        __builtin_amdgcn_s_setprio(0);
    LOOP3B_TAIL
    const int colbase = bn + wn;          // 64-aligned; section uniform per wave-half
    const int part = colbase >> 10;       // 0=q, 1=k, 2=v
    if (part < 2) {
        #pragma unroll
        for (int i = 0; i < 4; ++i) {
            #pragma unroll
            for (int r = 0; r < 4; ++r) {
                int row = bm + wm + 16 * i + fq * 4 + r;
                float cv0 = cs[row * 32 + frow],      sv0 = sn[row * 32 + frow];
                float cv1 = cs[row * 32 + 16 + frow], sv1 = sn[row * 32 + 16 + frow];
                float xa0 = acc[i][0][r], xa1 = acc[i][1][r];
                float xb0 = acc[i][2][r], xb1 = acc[i][3][r];
                ushort* dst = qkb + (size_t)row * QKS + (part << 10) + (colbase & 1023) + frow;
                dst[0]  = f2bf(xa0 * cv0 - xb0 * sv0);
                dst[16] = f2bf(xa1 * cv1 - xb1 * sv1);
                dst[32] = f2bf(xb0 * cv0 + xa0 * sv0);
                dst[48] = f2bf(xb1 * cv1 + xa1 * sv1);
            }
        }
    } else {
        const int hh = (colbase - 2048) >> 6;   // head (wave-uniform)
        #pragma unroll
        for (int i = 0; i < 4; ++i) {
            int row = bm + wm + 16 * i + (fq << 2);
            #pragma unroll
            for (int j = 0; j < 4; ++j) {
                int d = 16 * j + frow;
                ushort4 o4;
                o4.x = f2bf(acc[i][j][0]); o4.y = f2bf(acc[i][j][1]);
                o4.z = f2bf(acc[i][j][2]); o4.w = f2bf(acc[i][j][3]);
                *(ushort4*)(vT + ((size_t)hh * HD + d) * S_TOT + row) = o4;
            }
        }
    }
}

// ------- gate/up GEMM (128x128, 3-buf, swizzled, gu-interleaved) + fused SiLU -------
__global__ __launch_bounds__(256) void gemm3b_gu(
    const ushort* __restrict__ A, const ushort* __restrict__ B,
    ushort* __restrict__ gb, int K)
{
    constexpr int BM = 128, BN = 128;
    __shared__ ushort As[3][BM * 32];
    __shared__ ushort Bs[3][BN * 32];
    const int t = threadIdx.x;
    const int bm = blockIdx.x * BM, bn = blockIdx.y * BN;
    const int wave = t >> 6, lane = t & 63;
    const int wm = (wave & 1) * 64, wn = (wave >> 1) * 64;
    const int frow = lane & 15, fq = lane >> 4;
    STAGE_LAMBDA(2, 2)

    f32x4 acc[4][4];
    #pragma unroll
    for (int i = 0; i < 4; ++i)
        #pragma unroll
        for (int j = 0; j < 4; ++j) acc[i][j] = (f32x4){0.f, 0.f, 0.f, 0.f};

    const int NKT = K >> 5;
    LOOP3B_HEAD(4, 0)
        bf16x8 af[4], bfr[4];
        #pragma unroll
        for (int i = 0; i < 4; ++i) af[i] = LDS_A(i);
        #pragma unroll
        for (int j = 0; j < 4; ++j) bfr[j] = LDS_B(j);
        __builtin_amdgcn_s_setprio(1);
        #pragma unroll
        for (int i = 0; i < 4; ++i)
            #pragma unroll
            for (int j = 0; j < 4; ++j)
                acc[i][j] = __builtin_amdgcn_mfma_f32_16x16x32_bf16(
                    af[i], bfr[j], acc[i][j], 0, 0, 0);
        __builtin_amdgcn_s_setprio(0);
    LOOP3B_TAIL
    // fused SiLU: abs 16-col block even = gate, odd = up of same channels (same lane)
    #pragma unroll
    for (int i = 0; i < 4; ++i) {
        #pragma unroll
        for (int p = 0; p < 2; ++p) {
            int chan = ((bn + wn) >> 1) + p * 16 + frow;
            #pragma unroll
            for (int r = 0; r < 4; ++r) {
                int row = bm + wm + 16 * i + fq * 4 + r;
                float g = acc[i][2 * p][r], u = acc[i][2 * p + 1][r];
                float sg = 1.f / (1.f + __expf(-g));
                gb[(size_t)row * INTER + chan] = f2bf(g * sg * u);
            }
        }
    }
}

// ------- 3-buf split-K GEMM (swizzled): writes f32 partial slabs (no atomics) -------
template<int SPLITK>
__global__ __launch_bounds__(256) void gemm3b_sk(
    const ushort* __restrict__ A, const ushort* __restrict__ B,
    float* __restrict__ P, int M, int N, int K)
{
    constexpr int BM = 128, BN = 128;
    __shared__ ushort As[3][BM * 32];
    __shared__ ushort Bs[3][BN * 32];
    const int t = threadIdx.x;
    const int bm = blockIdx.x * BM, bn = blockIdx.y * BN;
    const int kc = K / SPLITK;
    const int kb = blockIdx.z * kc;
    const int wave = t >> 6, lane = t & 63;
    const int wm = (wave & 1) * 64, wn = (wave >> 1) * 64;
    const int frow = lane & 15, fq = lane >> 4;
    STAGE_LAMBDA(2, 2)

    f32x4 acc[4][4];
    #pragma unroll
    for (int i = 0; i < 4; ++i)
        #pragma unroll
        for (int j = 0; j < 4; ++j) acc[i][j] = (f32x4){0.f, 0.f, 0.f, 0.f};

    const int NKT = kc >> 5;
    LOOP3B_HEAD(4, kb)
        bf16x8 af[4], bfr[4];
        #pragma unroll
        for (int i = 0; i < 4; ++i) af[i] = LDS_A(i);
        #pragma unroll
        for (int j = 0; j < 4; ++j) bfr[j] = LDS_B(j);
        __builtin_amdgcn_s_setprio(1);
        #pragma unroll
        for (int i = 0; i < 4; ++i)
            #pragma unroll
            for (int j = 0; j < 4; ++j)
                acc[i][j] = __builtin_amdgcn_mfma_f32_16x16x32_bf16(
                    af[i], bfr[j], acc[i][j], 0, 0, 0);
        __builtin_amdgcn_s_setprio(0);
    LOOP3B_TAIL
    float* Pz = P + (size_t)blockIdx.z * M * N;
    #pragma unroll
    for (int i = 0; i < 4; ++i) {
        #pragma unroll
        for (int j = 0; j < 4; ++j) {
            #pragma unroll
            for (int r = 0; r < 4; ++r) {
                int row = bm + wm + 16 * i + fq * 4 + r;
                int col = bn + wn + 16 * j + frow;
                Pz[(size_t)row * N + col] = acc[i][j][r];
            }
        }
    }
}

// x[i] += P0[i] + P1[i] + P2[i] + P3[i]  (float4 vectorized; n4 = n/4)
__global__ __launch_bounds__(256) void reduce4_kernel(
    const float* __restrict__ P, float* __restrict__ x, int n4)
{
    int i = blockIdx.x * 256 + threadIdx.x;
    if (i >= n4) return;
    const int n = n4 << 2;
    float4 a  = ((const float4*)x)[i];
    float4 p0 = ((const float4*)P)[i];
    float4 p1 = ((const float4*)(P + (size_t)n))[i];
    float4 p2 = ((const float4*)(P + (size_t)2 * n))[i];
    float4 p3 = ((const float4*)(P + (size_t)3 * n))[i];
    a.x += p0.x + p1.x + p2.x + p3.x;
    a.y += p0.y + p1.y + p2.y + p3.y;
    a.z += p0.z + p1.z + p2.z + p3.z;
    a.w += p0.w + p1.w + p2.w + p3.w;
    ((float4*)x)[i] = a;
}

// fused: x += sum(4 partials); hnb = rms(x)*w   (one block per row)
__global__ __launch_bounds__(256) void reduce_rms_bf_kernel(
    const float* __restrict__ P, float* __restrict__ x,
    const float* __restrict__ w, ushort* __restrict__ out)
{
    int row = blockIdx.x, t = threadIdx.x;
    size_t off = (size_t)row * HID + t * 4;
    float4 a = *(const float4*)(x + off);
    #pragma unroll
    for (int z = 0; z < 4; ++z) {
        float4 p = *(const float4*)(P + (size_t)z * S_TOT * HID + off);
        a.x += p.x; a.y += p.y; a.z += p.z; a.w += p.w;
    }
    *(float4*)(x + off) = a;
    float ss = a.x * a.x + a.y * a.y + a.z * a.z + a.w * a.w;
    #pragma unroll
    for (int o = 32; o > 0; o >>= 1) ss += __shfl_down(ss, o, 64);
    __shared__ float red[4];
    int wid = t >> 6;
    if ((t & 63) == 0) red[wid] = ss;
    __syncthreads();
    if (t == 0)
        red[0] = rsqrtf((red[0] + red[1] + red[2] + red[3]) / HID + EPSV);
    __syncthreads();
    float rs = red[0];
    const float* wp = w + t * 4;
    ushort4 o4;
    o4.x = f2bf(a.x * rs * wp[0]); o4.y = f2bf(a.y * rs * wp[1]);
    o4.z = f2bf(a.z * rs * wp[2]); o4.w = f2bf(a.w * rs * wp[3]);
    *(ushort4*)(out + off) = o4;
}

// ---------------- RMS norm fp32->fp32 ----------------
__global__ __launch_bounds__(256) void rms_kernel(
    const float* __restrict__ in, const float* __restrict__ w,
    float* __restrict__ out)
{
    int row = blockIdx.x;
    const float* xr = in + (size_t)row * HID;
    float ss = 0.f;
    for (int i = threadIdx.x; i < HID; i += 256) { float v = xr[i]; ss += v * v; }
    #pragma unroll
    for (int off = 32; off > 0; off >>= 1) ss += __shfl_down(ss, off, 64);
    __shared__ float red[4];
    int wid = threadIdx.x >> 6;
    if ((threadIdx.x & 63) == 0) red[wid] = ss;
    __syncthreads();
    if (threadIdx.x == 0)
        red[0] = rsqrtf((red[0] + red[1] + red[2] + red[3]) / HID + EPSV);
    __syncthreads();
    float rs = red[0];
    for (int i = threadIdx.x; i < HID; i += 256)
        out[(size_t)row * HID + i] = xr[i] * rs * w[i];
}

// ---------------- RMS norm fp32->bf16 ----------------
__global__ __launch_bounds__(256) void rms_bf_kernel(
    const float* __restrict__ in, const float* __restrict__ w,
    ushort* __restrict__ out)
{
    int row = blockIdx.x;
    const float* xr = in + (size_t)row * HID;
    float ss = 0.f;
    for (int i = threadIdx.x; i < HID; i += 256) { float v = xr[i]; ss += v * v; }
    #pragma unroll
    for (int off = 32; off > 0; off >>= 1) ss += __shfl_down(ss, off, 64);
    __shared__ float red[4];
    int wid = threadIdx.x >> 6;
    if ((threadIdx.x & 63) == 0) red[wid] = ss;
    __syncthreads();
    if (threadIdx.x == 0)
        red[0] = rsqrtf((red[0] + red[1] + red[2] + red[3]) / HID + EPSV);
    __syncthreads();
    float rs = red[0];
    for (int i = threadIdx.x; i < HID; i += 256)
        out[(size_t)row * HID + i] = f2bf(xr[i] * rs * w[i]);
}

// ---------------- RoPE tables ----------------
__global__ void rope_tab_kernel(float* __restrict__ cs, float* __restrict__ sn)
{
    int s = blockIdx.x; int j = threadIdx.x; // 32 threads
    int h, w;
    if (s < S0) { h = s >> 5; w = s & 31; }
    else { int t = s - S0; h = t >> 4; w = t & 15; }
    float f;
    if (j < 16) f = (float)h * powf(10000.f, -(4.f * j) / 64.f);
    else        f = (float)w * powf(10000.f, -(4.f * (j - 16) + 2.f) / 64.f);
    cs[s * 32 + j] = cosf(f);
    sn[s * 32 + j] = sinf(f);
}

// ---------------- MFMA flash attention ----------------
__global__ __launch_bounds__(256) void flash_mfma_kernel(
    const ushort* __restrict__ qkb, const ushort* __restrict__ vT,
    ushort* __restrict__ o)
{
    __shared__ ushort Ks[64 * 72];
    __shared__ ushort Vt[64 * 72];
    __shared__ ushort Ps[4 * 16 * 72];
    int tile = blockIdx.x;
    int hh = blockIdx.y;
    int segStart, q0, nkt;
    if (tile < 16) { segStart = 0; q0 = tile << 6; nkt = 16; }
    else { segStart = S0; q0 = S0 + ((tile - 16) << 6); nkt = 8; }
    const int t = threadIdx.x;
    const int wave = t >> 6, lane = t & 63;
    const int c = lane & 15, fq = lane >> 4;
    const int wq = wave << 4;
    ushort* Pw = Ps + wave * 16 * 72;

    bf16x8 qf[2];
    #pragma unroll
    for (int ks = 0; ks < 2; ++ks)
        qf[ks] = *(const bf16x8*)(qkb + (size_t)(q0 + wq + c) * QKS + hh * HD + ks * 32 + fq * 8);

    float m_i[4], l_i[4];
    f32x4 accO[4];
    #pragma unroll
    for (int r = 0; r < 4; ++r) { m_i[r] = -1e30f; l_i[r] = 0.f; }
    #pragma unroll
    for (int nt = 0; nt < 4; ++nt) accO[nt] = (f32x4){0.f, 0.f, 0.f, 0.f};

    for (int kt = 0; kt < nkt; ++kt) {
        int kbase = segStart + (kt << 6);
        __syncthreads();
        #pragma unroll
        for (int i = 0; i < 2; ++i) {
            int u = t + (i << 8);
            int r = u >> 3, c8 = (u & 7) << 3;
            u16x8 kv = *(const u16x8*)(qkb + (size_t)(kbase + r) * QKS + 1024 + hh * HD + c8);
            *(u16x8*)(Ks + r * 72 + c8) = kv;
            u16x8 vv = *(const u16x8*)(vT + ((size_t)hh * HD + r) * S_TOT + kbase + c8);
            *(u16x8*)(Vt + r * 72 + c8) = vv;
        }
        __syncthreads();

        f32x4 acc[4];
        #pragma unroll
        for (int nt = 0; nt < 4; ++nt) acc[nt] = (f32x4){0.f, 0.f, 0.f, 0.f};
        #pragma unroll
        for (int ks = 0; ks < 2; ++ks) {
            #pragma unroll
            for (int nt = 0; nt < 4; ++nt) {
                bf16x8 bfr = *(const bf16x8*)(Ks + (nt * 16 + c) * 72 + ks * 32 + fq * 8);
                acc[nt] = __builtin_amdgcn_mfma_f32_16x16x32_bf16(qf[ks], bfr, acc[nt], 0, 0, 0);
            }
        }

        #pragma unroll
        for (int r = 0; r < 4; ++r) {
            float s0v = acc[0][r] * SCALEV, s1v = acc[1][r] * SCALEV;
            float s2v = acc[2][r] * SCALEV, s3v = acc[3][r] * SCALEV;
            float rm = fmaxf(fmaxf(s0v, s1v), fmaxf(s2v, s3v));
            #pragma unroll
            for (int msk = 1; msk < 16; msk <<= 1)
                rm = fmaxf(rm, __shfl_xor(rm, msk, 64));
            float mn = fmaxf(m_i[r], rm);
            float al = __expf(m_i[r] - mn);
            float p0 = __expf(s0v - mn), p1 = __expf(s1v - mn);
            float p2 = __expf(s2v - mn), p3 = __expf(s3v - mn);
            float rs = p0 + p1 + p2 + p3;
            #pragma unroll
            for (int msk = 1; msk < 16; msk <<= 1)
                rs += __shfl_xor(rs, msk, 64);
            l_i[r] = l_i[r] * al + rs;
            m_i[r] = mn;
            #pragma unroll
            for (int nt = 0; nt < 4; ++nt) accO[nt][r] *= al;
            int qrow = (fq << 2) + r;
            Pw[qrow * 72 + 0  + c] = f2bf(p0);
            Pw[qrow * 72 + 16 + c] = f2bf(p1);
            Pw[qrow * 72 + 32 + c] = f2bf(p2);
            Pw[qrow * 72 + 48 + c] = f2bf(p3);
        }

        #pragma unroll
        for (int ks = 0; ks < 2; ++ks) {
            bf16x8 pa = *(const bf16x8*)(Pw + c * 72 + ks * 32 + fq * 8);
            #pragma unroll
            for (int nt = 0; nt < 4; ++nt) {
                bf16x8 bv = *(const bf16x8*)(Vt + (nt * 16 + c) * 72 + ks * 32 + fq * 8);
                accO[nt] = __builtin_amdgcn_mfma_f32_16x16x32_bf16(pa, bv, accO[nt], 0, 0, 0);
            }
        }
    }

    #pragma unroll
    for (int r = 0; r < 4; ++r) {
        float inv = 1.f / l_i[r];
        int row = q0 + wq + (fq << 2) + r;
        #pragma unroll
        for (int nt = 0; nt < 4; ++nt)
            o[(size_t)row * HID + hh * HD + nt * 16 + c] = f2bf(accO[nt][r] * inv);
    }
}

// ---------------- copy to out ----------------
__global__ __launch_bounds__(256) void copy_kernel(
    const float* __restrict__ src, float* __restrict__ dst, int n)
{
    int i = blockIdx.x * 256 + threadIdx.x;
    if (i < n) dst[i] = src[i];
}

extern "C" void kernel_launch(void* const* d_in, const int* in_sizes, int n_in,
                              void* d_out, int out_size, void* d_ws, size_t ws_size,
                              hipStream_t stream)
{
    const float* img0        = (const float*)d_in[0];
    const float* img1        = (const float*)d_in[1];
    const float* conv_w      = (const float*)d_in[2];
    const float* ln_pre_w    = (const float*)d_in[3];
    const float* attn_norm_w = (const float*)d_in[4];
    const float* q_w         = (const float*)d_in[5];
    const float* k_w         = (const float*)d_in[6];
    const float* v_w         = (const float*)d_in[7];
    const float* o_w         = (const float*)d_in[8];
    const float* ffn_norm_w  = (const float*)d_in[9];
    const float* gate_w      = (const float*)d_in[10];
    const float* up_w        = (const float*)d_in[11];
    const float* down_w      = (const float*)d_in[12];

    char* p = (char*)d_ws;
    float* x    = (float*)p;   p += (size_t)1572864 * 4;   // [1536][1024]
    float* cs   = (float*)p;   p += (size_t)49152 * 4;
    float* sn   = (float*)p;   p += (size_t)49152 * 4;
    ushort* qkb = (ushort*)p;  p += (size_t)3145728 * 2;   // [1536][2048] rope'd q|k bf16
    ushort* vTb = (ushort*)p;  p += (size_t)1572864 * 2;   // [16][64][1536] V^T bf16
    ushort* hnb = (ushort*)p;  p += (size_t)1572864 * 2;   // [1536][1024]
    ushort* obb = (ushort*)p;  p += (size_t)1572864 * 2;   // [1536][1024]
    ushort* gb  = (ushort*)p;  p += (size_t)6291456 * 2;   // [1536][4096] silu(g)*u bf16
    float* skP  = (float*)p;   p += (size_t)6291456 * 4;   // 4 x [1536][1024] f32 partials
    ushort* Pb  = (ushort*)p;  p += (size_t)1179648 * 2;   // [1536][768]
    ushort* cvb = (ushort*)p;  p += (size_t)786432 * 2;    // conv_w bf16
    ushort* wbuf= (ushort*)p;  p += (size_t)16777216 * 2;  // per-layer weights

    ushort* wqkv = wbuf;                 // [3072][1024]
    ushort* wo   = wbuf + 3145728;       // [1024][1024]
    ushort* wgu  = wbuf + 4194304;       // [8192][1024] gu-interleaved
    ushort* wdn  = wbuf + 12582912;      // [1024][4096]

    dim3 blk(256);

    cvt_kernel<<<768, blk, 0, stream>>>(conv_w, cvb, 786432 / 4);
    im2col_kernel<<<S_TOT, blk, 0, stream>>>(img0, img1, Pb);
    gemm3b<64, 64, false><<<dim3(24, 16), blk, 0, stream>>>(
        Pb, cvb, x, S_TOT, HID, KCONV);
    rms_kernel<<<S_TOT, blk, 0, stream>>>(x, ln_pre_w, x);
    rope_tab_kernel<<<S_TOT, 32, 0, stream>>>(cs, sn);
    // first attn-norm hoisted out of the loop; later layers get it fused into
    // the down-proj reduction (reduce_rms_bf with attn_norm_w[l+1]).
    rms_bf_kernel<<<S_TOT, blk, 0, stream>>>(x, attn_norm_w, hnb);

    for (int l = 0; l < NLAYERS; ++l) {
        cvt_layer_kernel<<<16384, blk, 0, stream>>>(
            q_w + (size_t)l * 1048576, k_w + (size_t)l * 1048576,
            v_w + (size_t)l * 1048576, o_w + (size_t)l * 1048576,
            gate_w + (size_t)l * 4194304, up_w + (size_t)l * 4194304,
            down_w + (size_t)l * 4194304, wbuf);

        // qkv GEMM: fused RoPE (q,k -> qkb) + direct V^T write (v -> vTb)
        gemm3b_qkv<<<dim3(12, 24), blk, 0, stream>>>(
            hnb, wqkv, qkb, vTb, cs, sn, HID);
        flash_mfma_kernel<<<dim3(24, HEADS), blk, 0, stream>>>(qkb, vTb, obb);
        // o-projection: split-K partials, then fused (x += sum) + rms(ffn) -> hnb
        gemm3b_sk<4><<<dim3(12, 8, 4), blk, 0, stream>>>(
            obb, wo, skP, S_TOT, HID, HID);
        reduce_rms_bf_kernel<<<S_TOT, blk, 0, stream>>>(
            skP, x, ffn_norm_w + (size_t)l * HID, hnb);
        // gate/up GEMM: 128^2 3-buf swizzled, fused SiLU -> gb bf16
        gemm3b_gu<<<dim3(12, 64), blk, 0, stream>>>(hnb, wgu, gb, HID);
        // down-projection: split-K=4 partials; reduce fused with next attn-norm
        gemm3b_sk<4><<<dim3(12, 8, 4), blk, 0, stream>>>(
            gb, wdn, skP, S_TOT, HID, INTER);
        if (l + 1 < NLAYERS)
            reduce_rms_bf_kernel<<<S_TOT, blk, 0, stream>>>(
                skP, x, attn_norm_w + (size_t)(l + 1) * HID, hnb);
        else
            reduce4_kernel<<<1536, blk, 0, stream>>>(skP, x, S_TOT * HID / 4);
    }
    copy_kernel<<<(S_TOT * HID) / 256, blk, 0, stream>>>(x, (float*)d_out, S_TOT * HID);
}